// Round 13
// baseline (165.915 us; speedup 1.0000x reference)
//
#include <hip/hip_runtime.h>

typedef __attribute__((ext_vector_type(8))) short short8;   // 8 bf16 (4 VGPR)
typedef __attribute__((ext_vector_type(4))) float f32x4;    // MFMA acc

static const int NU = 100000;
static const int NM = 20000;
static const int NE = 600000;
static const int FEAT = 64;
static const int HID = 128;
static const int OUTD = 64;
static const int NTOT = NU + NM;
static const int CVT_TOT = 81920 + NM * FEAT;   // weights + movie_x
static const int CVT_BLKS = (CVT_TOT + 255) / 256;
static const int IDX_BLKS = (100000 + 255) / 256;

// bucket geometry: users 512 nodes/bucket, movies 128 nodes/bucket
static const int UB_SHIFT = 9;
static const int MB_SHIFT = 7;
static const int NBU = (NU + 511) >> 9;           // 196
static const int NBM = (NM + 127) >> 7;           // 157
static const int NBUCK = NBU + NBM;               // 353
static const int EPB = 4096;
static const int NPBLK = (NE + EPB - 1) / EPB;    // 147
static const int CAP = 8192;                      // fixed bucket capacity (2x headroom)
static const int Y1_BLKS = (NM + 127) / 128;      // 157
static const int GB2 = (NM + 15) / 16;            // 1250 (mean2 gather blocks)
static const int T3_BLKS = (NU + 127) / 128;      // 782

__device__ inline float b2f(unsigned short h) {
    unsigned int u = ((unsigned int)h) << 16;
    float f; __builtin_memcpy(&f, &u, 4); return f;
}
__device__ inline unsigned short f2b(float f) {
    unsigned int u; __builtin_memcpy(&u, &f, 4);
    u += 0x7FFFu + ((u >> 16) & 1u);            // RNE
    return (unsigned short)(u >> 16);
}
__device__ inline unsigned int pk2(float a, float b) {
    return (unsigned int)f2b(a) | ((unsigned int)f2b(b) << 16);
}
// XOR swizzle within a row: spreads 16B frag slots across banks (G4)
__device__ inline int wswz(int row, int bc, int rowbytes) {
    return row * rowbytes + (bc ^ ((row & 7) << 4));
}

// ---------------- pass 1 merged: edge partition (fixed-cap buckets) + cvt + idx + c1 ----------------
__global__ __launch_bounds__(256) void k_part_misc(
        const int* __restrict__ ui, const int* __restrict__ mi,
        int* __restrict__ gcur, int* __restrict__ entries,
        const float* __restrict__ w1l, const float* __restrict__ w2l,
        const float* __restrict__ w2r, const float* __restrict__ w3l,
        const float* __restrict__ w3r, const float* __restrict__ wl1,
        const float* __restrict__ wl2, const float* __restrict__ mx,
        unsigned short* __restrict__ dst,
        const int* __restrict__ tpl, float* __restrict__ oidx,
        const float* __restrict__ ue, const float* __restrict__ w1r,
        const float* __restrict__ b1, float* __restrict__ c1) {
    __shared__ int h[NBUCK], base[NBUCK], cur[NBUCK];
    const int b = blockIdx.x;
    const int tid = threadIdx.x;
    if (b < NPBLK) {
        for (int i = tid; i < NBUCK; i += 256) h[i] = 0;
        __syncthreads();
        int eu[EPB / 256], em[EPB / 256];
#pragma unroll
        for (int it = 0; it < EPB / 256; ++it) {
            int e = b * EPB + it * 256 + tid;
            if (e < NE) {
                eu[it] = ui[e]; em[it] = mi[e];
                atomicAdd(&h[eu[it] >> UB_SHIFT], 1);
                atomicAdd(&h[NBU + (em[it] >> MB_SHIFT)], 1);
            } else eu[it] = -1;
        }
        __syncthreads();
        for (int i = tid; i < NBUCK; i += 256) {
            int c = h[i];
            base[i] = c ? (i * CAP + atomicAdd(&gcur[i], c)) : 0;
            cur[i] = 0;
        }
        __syncthreads();
#pragma unroll
        for (int it = 0; it < EPB / 256; ++it) {
            if (eu[it] < 0) continue;
            int u = eu[it], m = em[it];
            int bu = u >> UB_SHIFT;
            int o1 = base[bu] + atomicAdd(&cur[bu], 1);
            entries[o1] = (m << UB_SHIFT) | (u & 511);
            int bm = NBU + (m >> MB_SHIFT);
            int o2 = base[bm] + atomicAdd(&cur[bm], 1);
            entries[o2] = (u << MB_SHIFT) | (m & 127);
        }
    } else if (b < NPBLK + CVT_BLKS) {
        int g = (b - NPBLK) * 256 + tid;
        if (g >= CVT_TOT) return;
        const float* s; int o;
        if      (g < 8192)   { s = w1l; o = g; }
        else if (g < 24576)  { s = w2l; o = g - 8192; }
        else if (g < 32768)  { s = w2r; o = g - 24576; }
        else if (g < 49152)  { s = w3l; o = g - 32768; }
        else if (g < 65536)  { s = w3r; o = g - 49152; }
        else if (g < 73728)  { s = wl1; o = g - 65536; }
        else if (g < 81920)  { s = wl2; o = g - 73728; }
        else                 { s = mx;  o = g - 81920; }
        dst[g] = f2b(s[o]);
    } else if (b < NPBLK + CVT_BLKS + IDX_BLKS) {
        int i = (b - NPBLK - CVT_BLKS) * 256 + tid;
        if (i < 100000) {
            oidx[i] = (float)tpl[i];
            oidx[100000 + i] = (float)(tpl[100000 + i] + NU);
        }
    } else {
        int hh = tid;
        if (hh < HID) {
            float a = 0.f;
#pragma unroll 16
            for (int k = 0; k < HID; ++k) a += ue[k] * w1r[hh * HID + k];
            c1[hh] = a + b1[hh];
        }
    }
}

// ---------------- pass 2 merged: per-bucket CSR build || Y1 = mxb @ W1l^T ----------------
__global__ __launch_bounds__(256) void k_csr_y1(
        const int* __restrict__ gcur, const int* __restrict__ entries,
        int2* __restrict__ rp2, int* __restrict__ list,
        const unsigned short* __restrict__ mxb, const unsigned short* __restrict__ W1l,
        unsigned short* __restrict__ Y1) {
    __shared__ __align__(16) char lds[16384];
    const int b = blockIdx.x;
    const int tid = threadIdx.x;
    if (b < NBUCK) {
        int* lcnt = (int*)lds;          // 512
        int* lrp  = lcnt + 512;         // 512
        int* lcur = lrp + 512;          // 512
        int* ps   = lcur + 512;         // 256
        const int s = b * CAP;
        const int e = s + gcur[b];
        const bool isU = b < NBU;
        const int shift = isU ? UB_SHIFT : MB_SHIFT;
        const int mask = isU ? 511 : 127;
        const int n0 = isU ? (b << UB_SHIFT) : ((b - NBU) << MB_SHIFT);
        const int nNodes = isU ? min(512, NU - n0) : min(128, NM - n0);
        const int g0 = isU ? n0 : NU + n0;

        for (int i = tid; i < 512; i += 256) { lcnt[i] = 0; lcur[i] = 0; }
        __syncthreads();
        for (int i = s + tid; i < e; i += 256)
            atomicAdd(&lcnt[entries[i] & mask], 1);
        __syncthreads();
        int a0 = lcnt[2 * tid], a1 = lcnt[2 * tid + 1];
        int pr = a0 + a1;
        ps[tid] = pr;
        __syncthreads();
#pragma unroll
        for (int off = 1; off < 256; off <<= 1) {
            int x = (tid >= off) ? ps[tid - off] : 0;
            __syncthreads();
            ps[tid] += x;
            __syncthreads();
        }
        int excl = ps[tid] - pr;
        lrp[2 * tid] = excl;
        lrp[2 * tid + 1] = excl + a0;
        __syncthreads();
        for (int i = tid; i < nNodes; i += 256)
            rp2[g0 + i] = make_int2(s + lrp[i], s + lrp[i] + lcnt[i]);
        for (int i = s + tid; i < e; i += 256) {
            int p = entries[i];
            int dl = p & mask;
            int off = s + lrp[dl] + atomicAdd(&lcur[dl], 1);
            list[off] = p >> shift;
        }
    } else {
        // Y1 GEMM: K=64, NO=128 (W1l rows 128B, staged swizzled in 16KB)
        const int gb = b - NBUCK;
        const int lane = tid & 63;
        const int wv = tid >> 6;
        const int rbase = gb * 128 + wv * 32;
        const int lr = lane & 15;
        const int kg = lane >> 4;
#pragma unroll
        for (int i = 0; i < 4; ++i) {
            int idx = tid + i * 256;
            int row = idx >> 3, bc = (idx & 7) << 4;
            *reinterpret_cast<uint4*>(lds + wswz(row, bc, 128)) =
                *reinterpret_cast<const uint4*>((const char*)W1l + idx * 16);
        }
        short8 xb[2][2];
#pragma unroll
        for (int t = 0; t < 2; ++t) {
            int row = min(rbase + t * 16 + lr, NM - 1);
#pragma unroll
            for (int kt = 0; kt < 2; ++kt)
                xb[t][kt] = *reinterpret_cast<const short8*>(
                    mxb + (size_t)row * FEAT + kt * 32 + kg * 8);
        }
        __syncthreads();
        f32x4 acc[2][8];
#pragma unroll
        for (int t = 0; t < 2; ++t)
#pragma unroll
            for (int c = 0; c < 8; ++c) acc[t][c] = (f32x4){0.f, 0.f, 0.f, 0.f};
#pragma unroll
        for (int cg = 0; cg < 8; ++cg) {
            short8 wf[2];
#pragma unroll
            for (int kt = 0; kt < 2; ++kt)
                wf[kt] = *reinterpret_cast<const short8*>(
                    lds + wswz(cg * 16 + lr, kt * 64 + kg * 16, 128));
#pragma unroll
            for (int kt = 0; kt < 2; ++kt)
#pragma unroll
                for (int t = 0; t < 2; ++t)
                    acc[t][cg] = __builtin_amdgcn_mfma_f32_16x16x32_bf16(
                        wf[kt], xb[t][kt], acc[t][cg], 0, 0, 0);
        }
#pragma unroll
        for (int t = 0; t < 2; ++t) {
            const int u = rbase + t * 16 + lr;
            if (u >= NM) continue;
#pragma unroll
            for (int cg = 0; cg < 8; ++cg) {
                const int h0 = cg * 16 + kg * 4;
                uint2 o = make_uint2(pk2(acc[t][cg][0], acc[t][cg][1]),
                                     pk2(acc[t][cg][2], acc[t][cg][3]));
                *reinterpret_cast<uint2*>(Y1 + (size_t)u * HID + h0) = o;
            }
        }
    }
}

// ---------------- gather + mean + c1 + relu epilogue (conv1) ----------------
__global__ __launch_bounds__(256) void k_gather_relu(const unsigned short* __restrict__ Y1,
                                                     const int2* __restrict__ rp2,
                                                     const int* __restrict__ list,
                                                     const float* __restrict__ c1,
                                                     unsigned short* __restrict__ user_x,
                                                     int n) {
    const int node = blockIdx.x * 16 + threadIdx.x / 16;
    if (node >= n) return;
    const int c8 = (threadIdx.x % 16) * 8;
    const int2 se = rp2[node];
    const int s = se.x, e = se.y;

    float a[8];
#pragma unroll
    for (int j = 0; j < 8; ++j) a[j] = 0.f;
    int i = s;
    for (; i + 3 < e; i += 4) {
        int r0 = list[i], r1 = list[i + 1], r2 = list[i + 2], r3 = list[i + 3];
        short8 v0 = *reinterpret_cast<const short8*>(Y1 + (size_t)r0 * HID + c8);
        short8 v1 = *reinterpret_cast<const short8*>(Y1 + (size_t)r1 * HID + c8);
        short8 v2 = *reinterpret_cast<const short8*>(Y1 + (size_t)r2 * HID + c8);
        short8 v3 = *reinterpret_cast<const short8*>(Y1 + (size_t)r3 * HID + c8);
#pragma unroll
        for (int j = 0; j < 8; ++j)
            a[j] += (b2f((unsigned short)v0[j]) + b2f((unsigned short)v1[j]))
                  + (b2f((unsigned short)v2[j]) + b2f((unsigned short)v3[j]));
    }
    for (; i < e; ++i) {
        int r0 = list[i];
        short8 v0 = *reinterpret_cast<const short8*>(Y1 + (size_t)r0 * HID + c8);
#pragma unroll
        for (int j = 0; j < 8; ++j) a[j] += b2f((unsigned short)v0[j]);
    }
    const float sc = 1.0f / (float)max(e - s, 1);
    float4 cv0 = *reinterpret_cast<const float4*>(c1 + c8);
    float4 cv1 = *reinterpret_cast<const float4*>(c1 + c8 + 4);
    float r[8];
    r[0] = fmaxf(a[0] * sc + cv0.x, 0.f); r[1] = fmaxf(a[1] * sc + cv0.y, 0.f);
    r[2] = fmaxf(a[2] * sc + cv0.z, 0.f); r[3] = fmaxf(a[3] * sc + cv0.w, 0.f);
    r[4] = fmaxf(a[4] * sc + cv1.x, 0.f); r[5] = fmaxf(a[5] * sc + cv1.y, 0.f);
    r[6] = fmaxf(a[6] * sc + cv1.z, 0.f); r[7] = fmaxf(a[7] * sc + cv1.w, 0.f);
    uint4 o;
    o.x = pk2(r[0], r[1]); o.y = pk2(r[2], r[3]);
    o.z = pk2(r[4], r[5]); o.w = pk2(r[6], r[7]);
    *reinterpret_cast<uint4*>(user_x + (size_t)node * HID + c8) = o;
}

// ---------------- merged: mean2 gather (movie side) || T3 = user_x @ W3r^T + b3 ----------------
__global__ __launch_bounds__(256) void k_g2t3(
        const unsigned short* __restrict__ user_x, const int2* __restrict__ rp2,
        const int* __restrict__ list, unsigned short* __restrict__ mean2,
        const unsigned short* __restrict__ W3r, const float* __restrict__ b3,
        unsigned short* __restrict__ T3) {
    __shared__ __align__(16) char lds[32768];
    const int b = blockIdx.x;
    const int tid = threadIdx.x;
    if (b < GB2) {
        // gather mean2 from user_x (movie-dst adjacency)
        const int node = b * 16 + tid / 16;
        if (node >= NM) return;
        const int c8 = (tid % 16) * 8;
        const int2 se = rp2[NU + node];
        const int s = se.x, e = se.y;
        float a[8];
#pragma unroll
        for (int j = 0; j < 8; ++j) a[j] = 0.f;
        int i = s;
        for (; i + 3 < e; i += 4) {
            int r0 = list[i], r1 = list[i + 1], r2 = list[i + 2], r3 = list[i + 3];
            short8 v0 = *reinterpret_cast<const short8*>(user_x + (size_t)r0 * HID + c8);
            short8 v1 = *reinterpret_cast<const short8*>(user_x + (size_t)r1 * HID + c8);
            short8 v2 = *reinterpret_cast<const short8*>(user_x + (size_t)r2 * HID + c8);
            short8 v3 = *reinterpret_cast<const short8*>(user_x + (size_t)r3 * HID + c8);
#pragma unroll
            for (int j = 0; j < 8; ++j)
                a[j] += (b2f((unsigned short)v0[j]) + b2f((unsigned short)v1[j]))
                      + (b2f((unsigned short)v2[j]) + b2f((unsigned short)v3[j]));
        }
        for (; i < e; ++i) {
            int r0 = list[i];
            short8 v0 = *reinterpret_cast<const short8*>(user_x + (size_t)r0 * HID + c8);
#pragma unroll
            for (int j = 0; j < 8; ++j) a[j] += b2f((unsigned short)v0[j]);
        }
        const float sc = 1.0f / (float)max(e - s, 1);
        short8 o;
#pragma unroll
        for (int j = 0; j < 8; ++j) o[j] = (short)f2b(a[j] * sc);
        *reinterpret_cast<short8*>(mean2 + (size_t)node * HID + c8) = o;
    } else {
        // T3 GEMM: K=128, NO=128, W3r staged (32KB)
        const int gb = b - GB2;
        const int lane = tid & 63;
        const int wv = tid >> 6;
        const int rbase = gb * 128 + wv * 32;
        const int lr = lane & 15;
        const int kg = lane >> 4;
#pragma unroll
        for (int i = 0; i < 8; ++i) {
            int idx = tid + i * 256;
            int row = idx >> 4, bc = (idx & 15) << 4;
            *reinterpret_cast<uint4*>(lds + wswz(row, bc, 256)) =
                *reinterpret_cast<const uint4*>((const char*)W3r + idx * 16);
        }
        short8 xb[2][4];
#pragma unroll
        for (int t = 0; t < 2; ++t) {
            int row = min(rbase + t * 16 + lr, NU - 1);
#pragma unroll
            for (int kt = 0; kt < 4; ++kt)
                xb[t][kt] = *reinterpret_cast<const short8*>(
                    user_x + (size_t)row * HID + kt * 32 + kg * 8);
        }
        __syncthreads();
        f32x4 acc[2][8];
#pragma unroll
        for (int t = 0; t < 2; ++t)
#pragma unroll
            for (int c = 0; c < 8; ++c) acc[t][c] = (f32x4){0.f, 0.f, 0.f, 0.f};
#pragma unroll
        for (int cg = 0; cg < 8; ++cg) {
            short8 wf[4];
#pragma unroll
            for (int kt = 0; kt < 4; ++kt)
                wf[kt] = *reinterpret_cast<const short8*>(
                    lds + wswz(cg * 16 + lr, kt * 64 + kg * 16, 256));
#pragma unroll
            for (int kt = 0; kt < 4; ++kt)
#pragma unroll
                for (int t = 0; t < 2; ++t)
                    acc[t][cg] = __builtin_amdgcn_mfma_f32_16x16x32_bf16(
                        wf[kt], xb[t][kt], acc[t][cg], 0, 0, 0);
        }
#pragma unroll
        for (int t = 0; t < 2; ++t) {
            const int u = rbase + t * 16 + lr;
            if (u >= NU) continue;
#pragma unroll
            for (int cg = 0; cg < 8; ++cg) {
                const int h0 = cg * 16 + kg * 4;
                float4 vv = *reinterpret_cast<const float4*>(b3 + h0);
                uint2 o = make_uint2(pk2(acc[t][cg][0] + vv.x, acc[t][cg][1] + vv.y),
                                     pk2(acc[t][cg][2] + vv.z, acc[t][cg][3] + vv.w));
                *reinterpret_cast<uint2*>(T3 + (size_t)u * HID + h0) = o;
            }
        }
    }
}

// ---------------- gather Y3 -> Z = relu(mean + T3) (conv3 node update inline) ----------------
__global__ __launch_bounds__(256) void k_gather_z(const unsigned short* __restrict__ Y3,
                                                  const int2* __restrict__ rp2,
                                                  const int* __restrict__ list,
                                                  const unsigned short* __restrict__ T3,
                                                  unsigned short* __restrict__ Z, int n) {
    const int node = blockIdx.x * 16 + threadIdx.x / 16;
    if (node >= n) return;
    const int c8 = (threadIdx.x % 16) * 8;
    const int2 se = rp2[node];
    const int s = se.x, e = se.y;

    float a[8];
#pragma unroll
    for (int j = 0; j < 8; ++j) a[j] = 0.f;
    int i = s;
    for (; i + 3 < e; i += 4) {
        int r0 = list[i], r1 = list[i + 1], r2 = list[i + 2], r3 = list[i + 3];
        short8 v0 = *reinterpret_cast<const short8*>(Y3 + (size_t)r0 * HID + c8);
        short8 v1 = *reinterpret_cast<const short8*>(Y3 + (size_t)r1 * HID + c8);
        short8 v2 = *reinterpret_cast<const short8*>(Y3 + (size_t)r2 * HID + c8);
        short8 v3 = *reinterpret_cast<const short8*>(Y3 + (size_t)r3 * HID + c8);
#pragma unroll
        for (int j = 0; j < 8; ++j)
            a[j] += (b2f((unsigned short)v0[j]) + b2f((unsigned short)v1[j]))
                  + (b2f((unsigned short)v2[j]) + b2f((unsigned short)v3[j]));
    }
    for (; i < e; ++i) {
        int r0 = list[i];
        short8 v0 = *reinterpret_cast<const short8*>(Y3 + (size_t)r0 * HID + c8);
#pragma unroll
        for (int j = 0; j < 8; ++j) a[j] += b2f((unsigned short)v0[j]);
    }
    const float sc = 1.0f / (float)max(e - s, 1);
    short8 t3 = *reinterpret_cast<const short8*>(T3 + (size_t)node * HID + c8);
    short8 o;
#pragma unroll
    for (int j = 0; j < 8; ++j)
        o[j] = (short)f2b(fmaxf(a[j] * sc + b2f((unsigned short)t3[j]), 0.f));
    *reinterpret_cast<short8*>(Z + (size_t)node * HID + c8) = o;
}

// ================= swapped-operand MFMA GEMM, W staged in LDS =================
template<int K, int NO, bool AVEC, bool RELU, bool F32OUT>
__global__ __launch_bounds__(256) void k_mf2(const unsigned short* __restrict__ X,
                                             const unsigned short* __restrict__ W,
                                             const float* __restrict__ vec,
                                             void* __restrict__ Yv, int M) {
    constexpr int KT = K / 32;
    constexpr int CG = NO / 16;
    constexpr int WB = NO * K * 2;
    constexpr int RB = K * 2;
    __shared__ __align__(16) char lds[WB];
    const int tid = threadIdx.x;
    const int lane = tid & 63;
    const int wv = tid >> 6;
    const int rbase = blockIdx.x * 128 + wv * 32;
    const int lr = lane & 15;
    const int kg = lane >> 4;

#pragma unroll
    for (int i = 0; i < WB / 16 / 256; ++i) {
        int idx = tid + i * 256;
        int row = idx / (RB / 16);
        int bc = (idx % (RB / 16)) * 16;
        *reinterpret_cast<uint4*>(lds + wswz(row, bc, RB)) =
            *reinterpret_cast<const uint4*>((const char*)W + idx * 16);
    }

    short8 xb[2][KT];
#pragma unroll
    for (int t = 0; t < 2; ++t) {
        int row = min(rbase + t * 16 + lr, M - 1);
#pragma unroll
        for (int kt = 0; kt < KT; ++kt)
            xb[t][kt] = *reinterpret_cast<const short8*>(
                X + (size_t)row * K + kt * 32 + kg * 8);
    }
    __syncthreads();

    f32x4 acc[2][CG];
#pragma unroll
    for (int t = 0; t < 2; ++t)
#pragma unroll
        for (int c = 0; c < CG; ++c) acc[t][c] = (f32x4){0.f, 0.f, 0.f, 0.f};

#pragma unroll
    for (int cg = 0; cg < CG; ++cg) {
        short8 wf[KT];
#pragma unroll
        for (int kt = 0; kt < KT; ++kt)
            wf[kt] = *reinterpret_cast<const short8*>(
                lds + wswz(cg * 16 + lr, kt * 64 + kg * 16, RB));
#pragma unroll
        for (int kt = 0; kt < KT; ++kt)
#pragma unroll
            for (int t = 0; t < 2; ++t)
                acc[t][cg] = __builtin_amdgcn_mfma_f32_16x16x32_bf16(
                    wf[kt], xb[t][kt], acc[t][cg], 0, 0, 0);
    }

#pragma unroll
    for (int t = 0; t < 2; ++t) {
        const int u = rbase + t * 16 + lr;
        if (u >= M) continue;
#pragma unroll
        for (int cg = 0; cg < CG; ++cg) {
            const int h0 = cg * 16 + kg * 4;
            float v[4];
#pragma unroll
            for (int r = 0; r < 4; ++r) v[r] = acc[t][cg][r];
            if (AVEC) {
                float4 vv = *reinterpret_cast<const float4*>(vec + h0);
                v[0] += vv.x; v[1] += vv.y; v[2] += vv.z; v[3] += vv.w;
            }
            if (RELU)
#pragma unroll
                for (int r = 0; r < 4; ++r) v[r] = fmaxf(v[r], 0.f);
            if (F32OUT) {
                float4 o = make_float4(v[0], v[1], v[2], v[3]);
                *reinterpret_cast<float4*>((float*)Yv + (size_t)u * NO + h0) = o;
            } else {
                uint2 o = make_uint2(pk2(v[0], v[1]), pk2(v[2], v[3]));
                *reinterpret_cast<uint2*>((unsigned short*)Yv + (size_t)u * NO + h0) = o;
            }
        }
    }
}

// ================= fused movie chain + Y3 projection =================
__global__ __launch_bounds__(256) void k_fused_m(
        const unsigned short* __restrict__ mean2, const unsigned short* __restrict__ mxb,
        const unsigned short* __restrict__ W2l, const unsigned short* __restrict__ W2r,
        const float* __restrict__ b2, unsigned short* __restrict__ movie_z,
        const unsigned short* __restrict__ Wl2, const float* __restrict__ bl2,
        const unsigned short* __restrict__ W3l, unsigned short* __restrict__ Y3,
        float* __restrict__ out, int M) {
    __shared__ __align__(16) char lds[65536];
    // [0,32K) W2l -> Z; [32K,48K) W2r -> W3l(lo); [48K,64K) Wl2 -> W3l(hi)
    const int tid = threadIdx.x;
    const int lane = tid & 63;
    const int wv = tid >> 6;
    const int rbase = blockIdx.x * 128 + wv * 32;
    const int lr = lane & 15;
    const int kg = lane >> 4;

#pragma unroll
    for (int i = 0; i < 8; ++i) {
        int idx = tid + i * 256;
        int row = idx >> 4, bc = (idx & 15) << 4;
        *reinterpret_cast<uint4*>(lds + wswz(row, bc, 256)) =
            *reinterpret_cast<const uint4*>((const char*)W2l + idx * 16);
    }
#pragma unroll
    for (int i = 0; i < 4; ++i) {
        int idx = tid + i * 256;
        int row = idx >> 3, bc = (idx & 7) << 4;
        *reinterpret_cast<uint4*>(lds + 32768 + wswz(row, bc, 128)) =
            *reinterpret_cast<const uint4*>((const char*)W2r + idx * 16);
        int row2 = idx >> 4, bc2 = (idx & 15) << 4;
        *reinterpret_cast<uint4*>(lds + 49152 + wswz(row2, bc2, 256)) =
            *reinterpret_cast<const uint4*>((const char*)Wl2 + idx * 16);
    }

    short8 xa[2][4], xc[2][2];
#pragma unroll
    for (int t = 0; t < 2; ++t) {
        int row = min(rbase + t * 16 + lr, M - 1);
#pragma unroll
        for (int kt = 0; kt < 4; ++kt)
            xa[t][kt] = *reinterpret_cast<const short8*>(
                mean2 + (size_t)row * HID + kt * 32 + kg * 8);
#pragma unroll
        for (int kt = 0; kt < 2; ++kt)
            xc[t][kt] = *reinterpret_cast<const short8*>(
                mxb + (size_t)row * FEAT + kt * 32 + kg * 8);
    }
    __syncthreads();

    f32x4 acc[2][8];
#pragma unroll
    for (int t = 0; t < 2; ++t)
#pragma unroll
        for (int c = 0; c < 8; ++c) acc[t][c] = (f32x4){0.f, 0.f, 0.f, 0.f};

#pragma unroll
    for (int cg = 0; cg < 8; ++cg) {
        short8 wl[4], wr[2];
#pragma unroll
        for (int kt = 0; kt < 4; ++kt)
            wl[kt] = *reinterpret_cast<const short8*>(
                lds + wswz(cg * 16 + lr, kt * 64 + kg * 16, 256));
#pragma unroll
        for (int kt = 0; kt < 2; ++kt)
            wr[kt] = *reinterpret_cast<const short8*>(
                lds + 32768 + wswz(cg * 16 + lr, kt * 64 + kg * 16, 128));
#pragma unroll
        for (int kt = 0; kt < 4; ++kt)
#pragma unroll
            for (int t = 0; t < 2; ++t)
                acc[t][cg] = __builtin_amdgcn_mfma_f32_16x16x32_bf16(
                    wl[kt], xa[t][kt], acc[t][cg], 0, 0, 0);
#pragma unroll
        for (int kt = 0; kt < 2; ++kt)
#pragma unroll
            for (int t = 0; t < 2; ++t)
                acc[t][cg] = __builtin_amdgcn_mfma_f32_16x16x32_bf16(
                    wr[kt], xc[t][kt], acc[t][cg], 0, 0, 0);
    }
    __syncthreads();   // W2l reads done -> Z may overwrite [0,32K)

    // epilogue 1: relu(acc + b2) -> Z (LDS) + global movie_z
#pragma unroll
    for (int t = 0; t < 2; ++t) {
        const int ul = wv * 32 + t * 16 + lr;
        const int u = rbase + t * 16 + lr;
#pragma unroll
        for (int cg = 0; cg < 8; ++cg) {
            const int h0 = cg * 16 + kg * 4;
            float4 vv = *reinterpret_cast<const float4*>(b2 + h0);
            float v0 = fmaxf(acc[t][cg][0] + vv.x, 0.f);
            float v1 = fmaxf(acc[t][cg][1] + vv.y, 0.f);
            float v2 = fmaxf(acc[t][cg][2] + vv.z, 0.f);
            float v3 = fmaxf(acc[t][cg][3] + vv.w, 0.f);
            uint2 pk = make_uint2(pk2(v0, v1), pk2(v2, v3));
            *reinterpret_cast<uint2*>(lds + wswz(ul, h0 * 2, 256)) = pk;
            if (u < M)
                *reinterpret_cast<uint2*>(movie_z + (size_t)u * HID + h0) = pk;
        }
    }
    __syncthreads();

    // GEMM2: out = Z @ Wlin2^T + blin2
    short8 zb[2][4];
#pragma unroll
    for (int t = 0; t < 2; ++t) {
        const int ul = wv * 32 + t * 16 + lr;
#pragma unroll
        for (int kt = 0; kt < 4; ++kt)
            zb[t][kt] = *reinterpret_cast<const short8*>(
                lds + wswz(ul, kt * 64 + kg * 16, 256));
    }
    f32x4 a2[2][4];
#pragma unroll
    for (int t = 0; t < 2; ++t)
#pragma unroll
        for (int c = 0; c < 4; ++c) a2[t][c] = (f32x4){0.f, 0.f, 0.f, 0.f};
#pragma unroll
    for (int cg = 0; cg < 4; ++cg) {
        short8 wf[4];
#pragma unroll
        for (int kt = 0; kt < 4; ++kt)
            wf[kt] = *reinterpret_cast<const short8*>(
                lds + 49152 + wswz(cg * 16 + lr, kt * 64 + kg * 16, 256));
#pragma unroll
        for (int kt = 0; kt < 4; ++kt)
#pragma unroll
            for (int t = 0; t < 2; ++t)
                a2[t][cg] = __builtin_amdgcn_mfma_f32_16x16x32_bf16(
                    wf[kt], zb[t][kt], a2[t][cg], 0, 0, 0);
    }
#pragma unroll
    for (int t = 0; t < 2; ++t) {
        const int u = rbase + t * 16 + lr;
        if (u >= M) continue;
#pragma unroll
        for (int cg = 0; cg < 4; ++cg) {
            const int o0 = cg * 16 + kg * 4;
            float4 bb = *reinterpret_cast<const float4*>(bl2 + o0);
            float4 o = make_float4(a2[t][cg][0] + bb.x, a2[t][cg][1] + bb.y,
                                   a2[t][cg][2] + bb.z, a2[t][cg][3] + bb.w);
            *reinterpret_cast<float4*>(out + (size_t)u * OUTD + o0) = o;
        }
    }
    __syncthreads();   // Wl2 + W2r reads done -> W3l may overwrite [32K,64K)

    // stage W3l (32KB, 256B rows) at [32K,64K)
#pragma unroll
    for (int i = 0; i < 8; ++i) {
        int idx = tid + i * 256;
        int row = idx >> 4, bc = (idx & 15) << 4;
        *reinterpret_cast<uint4*>(lds + 32768 + wswz(row, bc, 256)) =
            *reinterpret_cast<const uint4*>((const char*)W3l + idx * 16);
    }
    __syncthreads();

    // GEMM3: Y3 = Z @ W3l^T
    f32x4 a3[2][8];
#pragma unroll
    for (int t = 0; t < 2; ++t)
#pragma unroll
        for (int c = 0; c < 8; ++c) a3[t][c] = (f32x4){0.f, 0.f, 0.f, 0.f};
#pragma unroll
    for (int cg = 0; cg < 8; ++cg) {
        short8 wf[4];
#pragma unroll
        for (int kt = 0; kt < 4; ++kt)
            wf[kt] = *reinterpret_cast<const short8*>(
                lds + 32768 + wswz(cg * 16 + lr, kt * 64 + kg * 16, 256));
#pragma unroll
        for (int kt = 0; kt < 4; ++kt)
#pragma unroll
            for (int t = 0; t < 2; ++t)
                a3[t][cg] = __builtin_amdgcn_mfma_f32_16x16x32_bf16(
                    wf[kt], zb[t][kt], a3[t][cg], 0, 0, 0);
    }
#pragma unroll
    for (int t = 0; t < 2; ++t) {
        const int u = rbase + t * 16 + lr;
        if (u >= M) continue;
#pragma unroll
        for (int cg = 0; cg < 8; ++cg) {
            const int h0 = cg * 16 + kg * 4;
            uint2 pk = make_uint2(pk2(a3[t][cg][0], a3[t][cg][1]),
                                  pk2(a3[t][cg][2], a3[t][cg][3]));
            *reinterpret_cast<uint2*>(Y3 + (size_t)u * HID + h0) = pk;
        }
    }
}

extern "C" void kernel_launch(void* const* d_in, const int* in_sizes, int n_in,
                              void* d_out, int out_size, void* d_ws, size_t ws_size,
                              hipStream_t stream) {
    const float* movie_x  = (const float*)d_in[0];
    const int*   user_idx = (const int*)d_in[1];
    const int*   movie_idx= (const int*)d_in[2];
    const int*   tuples   = (const int*)d_in[3];
    const float* user_emb = (const float*)d_in[4];
    const float* W1l = (const float*)d_in[5];
    const float* b1  = (const float*)d_in[6];
    const float* W1r = (const float*)d_in[7];
    const float* W2l = (const float*)d_in[8];
    const float* b2  = (const float*)d_in[9];
    const float* W2r = (const float*)d_in[10];
    const float* W3l = (const float*)d_in[11];
    const float* b3  = (const float*)d_in[12];
    const float* W3r = (const float*)d_in[13];
    const float* Wlin1 = (const float*)d_in[14];
    const float* blin1 = (const float*)d_in[15];
    const float* Wlin2 = (const float*)d_in[16];
    const float* blin2 = (const float*)d_in[17];

    float* out = (float*)d_out;

    // ---- workspace layout ----
    char* p = (char*)d_ws;
    int* gcur = (int*)p;  p += 360 * 4;
    int* entries = (int*)p; p += (size_t)NBUCK * CAP * 4;
    int2* rp2  = (int2*)p; p += (size_t)NTOT * 8;
    int* list  = (int*)p;  p += (size_t)NBUCK * CAP * 4;
    float* c1  = (float*)p; p += 128 * 4;
    unsigned short* wb = (unsigned short*)p; p += (size_t)CVT_TOT * 2;
    unsigned short* W1l_b  = wb;
    unsigned short* W2l_b  = wb + 8192;
    unsigned short* W2r_b  = wb + 24576;
    unsigned short* W3l_b  = wb + 32768;
    unsigned short* W3r_b  = wb + 49152;
    unsigned short* Wlin1_b= wb + 65536;
    unsigned short* Wlin2_b= wb + 73728;
    unsigned short* mxb    = wb + 81920;                              // [NM][64]
    unsigned short* Y1     = (unsigned short*)p; p += (size_t)NM * HID * 2;
    unsigned short* user_x = (unsigned short*)p; p += (size_t)NU * HID * 2;
    unsigned short* mean2  = (unsigned short*)p; p += (size_t)NM * HID * 2;
    unsigned short* movie_z= (unsigned short*)p; p += (size_t)NM * HID * 2;
    unsigned short* Y3     = (unsigned short*)p; p += (size_t)NM * HID * 2;
    unsigned short* T3     = (unsigned short*)p; p += (size_t)NU * HID * 2;
    unsigned short* Z      = (unsigned short*)p; p += (size_t)NU * HID * 2;

    // ---- pass 1: partition (fixed-cap buckets) + cvt + idx + c1 ----
    hipMemsetAsync(gcur, 0, NBUCK * sizeof(int), stream);
    k_part_misc<<<NPBLK + CVT_BLKS + IDX_BLKS + 1, 256, 0, stream>>>(
        user_idx, movie_idx, gcur, entries,
        W1l, W2l, W2r, W3l, W3r, Wlin1, Wlin2, movie_x, wb,
        tuples, out + (size_t)(NU + NM) * OUTD, user_emb, W1r, b1, c1);

    // ---- pass 2: per-bucket CSR || Y1 = movie_x @ W1l^T (independent) ----
    k_csr_y1<<<NBUCK + Y1_BLKS, 256, 0, stream>>>(gcur, entries, rp2, list,
                                                  mxb, W1l_b, Y1);

    // ---- conv1: gather(Y1) + c1 + relu -> user_x ----
    k_gather_relu<<<(NU + 15) / 16, 256, 0, stream>>>(Y1, rp2, list, c1, user_x, NU);

    // ---- mean2 gather || T3 = user_x @ W3r^T + b3 (co-dispatched, both need only user_x) ----
    k_g2t3<<<GB2 + T3_BLKS, 256, 0, stream>>>(user_x, rp2, list, mean2, W3r_b, b3, T3);

    // ---- conv2 + lin2 + Y3 projection ----
    k_fused_m<<<(NM + 127) / 128, 256, 0, stream>>>(
        mean2, mxb, W2l_b, W2r_b, b2, movie_z, Wlin2_b, blin2, W3l_b, Y3,
        out + (size_t)NU * OUTD, NM);

    // ---- conv3: gather(Y3) + T3 + relu -> Z ----
    k_gather_z<<<(NU + 15) / 16, 256, 0, stream>>>(Y3, rp2, list, T3, Z, NU);

    // ---- lin1: out = Z @ Wlin1^T + blin1 ----
    k_mf2<HID, OUTD, true, false, true><<<(NU + 127) / 128, 256, 0, stream>>>(
        Z, Wlin1_b, blin1, out, NU);
}

// Round 14
// 161.272 us; speedup vs baseline: 1.0288x; 1.0288x over previous
//
#include <hip/hip_runtime.h>

typedef __attribute__((ext_vector_type(8))) short short8;   // 8 bf16 (4 VGPR)
typedef __attribute__((ext_vector_type(4))) float f32x4;    // MFMA acc

static const int NU = 100000;
static const int NM = 20000;
static const int NE = 600000;
static const int FEAT = 64;
static const int HID = 128;
static const int OUTD = 64;
static const int NTOT = NU + NM;
static const int CVT_TOT = 81920 + NM * FEAT;   // weights + movie_x
static const int CVT_BLKS = (CVT_TOT + 255) / 256;
static const int IDX_BLKS = (100000 + 255) / 256;

// bucket geometry: users 512 nodes/bucket, movies 128 nodes/bucket
static const int UB_SHIFT = 9;
static const int MB_SHIFT = 7;
static const int NBU = (NU + 511) >> 9;           // 196
static const int NBM = (NM + 127) >> 7;           // 157
static const int NBUCK = NBU + NBM;               // 353
static const int EPB = 4096;
static const int NPBLK = (NE + EPB - 1) / EPB;    // 147
static const int CAP = 8192;                      // fixed bucket capacity (2x headroom)
static const int Y1_BLKS = (NM + 127) / 128;      // 157
static const int FM_BLKS = (NM + 127) / 128;      // 157 (fused movie chain)
static const int T3_BLKS = (NU + 127) / 128;      // 782

__device__ inline float b2f(unsigned short h) {
    unsigned int u = ((unsigned int)h) << 16;
    float f; __builtin_memcpy(&f, &u, 4); return f;
}
__device__ inline unsigned short f2b(float f) {
    unsigned int u; __builtin_memcpy(&u, &f, 4);
    u += 0x7FFFu + ((u >> 16) & 1u);            // RNE
    return (unsigned short)(u >> 16);
}
__device__ inline unsigned int pk2(float a, float b) {
    return (unsigned int)f2b(a) | ((unsigned int)f2b(b) << 16);
}
// XOR swizzle within a row: spreads 16B frag slots across banks (G4)
__device__ inline int wswz(int row, int bc, int rowbytes) {
    return row * rowbytes + (bc ^ ((row & 7) << 4));
}

// ---------------- pass 1 merged: edge partition (fixed-cap buckets) + cvt + idx + c1 ----------------
__global__ __launch_bounds__(256) void k_part_misc(
        const int* __restrict__ ui, const int* __restrict__ mi,
        int* __restrict__ gcur, int* __restrict__ entries,
        const float* __restrict__ w1l, const float* __restrict__ w2l,
        const float* __restrict__ w2r, const float* __restrict__ w3l,
        const float* __restrict__ w3r, const float* __restrict__ wl1,
        const float* __restrict__ wl2, const float* __restrict__ mx,
        unsigned short* __restrict__ dst,
        const int* __restrict__ tpl, float* __restrict__ oidx,
        const float* __restrict__ ue, const float* __restrict__ w1r,
        const float* __restrict__ b1, float* __restrict__ c1) {
    __shared__ int h[NBUCK], base[NBUCK], cur[NBUCK];
    const int b = blockIdx.x;
    const int tid = threadIdx.x;
    if (b < NPBLK) {
        for (int i = tid; i < NBUCK; i += 256) h[i] = 0;
        __syncthreads();
        int eu[EPB / 256], em[EPB / 256];
#pragma unroll
        for (int it = 0; it < EPB / 256; ++it) {
            int e = b * EPB + it * 256 + tid;
            if (e < NE) {
                eu[it] = ui[e]; em[it] = mi[e];
                atomicAdd(&h[eu[it] >> UB_SHIFT], 1);
                atomicAdd(&h[NBU + (em[it] >> MB_SHIFT)], 1);
            } else eu[it] = -1;
        }
        __syncthreads();
        for (int i = tid; i < NBUCK; i += 256) {
            int c = h[i];
            base[i] = c ? (i * CAP + atomicAdd(&gcur[i], c)) : 0;
            cur[i] = 0;
        }
        __syncthreads();
#pragma unroll
        for (int it = 0; it < EPB / 256; ++it) {
            if (eu[it] < 0) continue;
            int u = eu[it], m = em[it];
            int bu = u >> UB_SHIFT;
            int o1 = base[bu] + atomicAdd(&cur[bu], 1);
            entries[o1] = (m << UB_SHIFT) | (u & 511);
            int bm = NBU + (m >> MB_SHIFT);
            int o2 = base[bm] + atomicAdd(&cur[bm], 1);
            entries[o2] = (u << MB_SHIFT) | (m & 127);
        }
    } else if (b < NPBLK + CVT_BLKS) {
        int g = (b - NPBLK) * 256 + tid;
        if (g >= CVT_TOT) return;
        const float* s; int o;
        if      (g < 8192)   { s = w1l; o = g; }
        else if (g < 24576)  { s = w2l; o = g - 8192; }
        else if (g < 32768)  { s = w2r; o = g - 24576; }
        else if (g < 49152)  { s = w3l; o = g - 32768; }
        else if (g < 65536)  { s = w3r; o = g - 49152; }
        else if (g < 73728)  { s = wl1; o = g - 65536; }
        else if (g < 81920)  { s = wl2; o = g - 73728; }
        else                 { s = mx;  o = g - 81920; }
        dst[g] = f2b(s[o]);
    } else if (b < NPBLK + CVT_BLKS + IDX_BLKS) {
        int i = (b - NPBLK - CVT_BLKS) * 256 + tid;
        if (i < 100000) {
            oidx[i] = (float)tpl[i];
            oidx[100000 + i] = (float)(tpl[100000 + i] + NU);
        }
    } else {
        int hh = tid;
        if (hh < HID) {
            float a = 0.f;
#pragma unroll 16
            for (int k = 0; k < HID; ++k) a += ue[k] * w1r[hh * HID + k];
            c1[hh] = a + b1[hh];
        }
    }
}

// ---------------- pass 2 merged: per-bucket CSR build || Y1 = mxb @ W1l^T ----------------
__global__ __launch_bounds__(256) void k_csr_y1(
        const int* __restrict__ gcur, const int* __restrict__ entries,
        int2* __restrict__ rp2, int* __restrict__ list,
        const unsigned short* __restrict__ mxb, const unsigned short* __restrict__ W1l,
        unsigned short* __restrict__ Y1) {
    __shared__ __align__(16) char lds[16384];
    const int b = blockIdx.x;
    const int tid = threadIdx.x;
    if (b < NBUCK) {
        int* lcnt = (int*)lds;          // 512
        int* lrp  = lcnt + 512;         // 512
        int* lcur = lrp + 512;          // 512
        int* ps   = lcur + 512;         // 256
        const int s = b * CAP;
        const int e = s + gcur[b];
        const bool isU = b < NBU;
        const int shift = isU ? UB_SHIFT : MB_SHIFT;
        const int mask = isU ? 511 : 127;
        const int n0 = isU ? (b << UB_SHIFT) : ((b - NBU) << MB_SHIFT);
        const int nNodes = isU ? min(512, NU - n0) : min(128, NM - n0);
        const int g0 = isU ? n0 : NU + n0;

        for (int i = tid; i < 512; i += 256) { lcnt[i] = 0; lcur[i] = 0; }
        __syncthreads();
        for (int i = s + tid; i < e; i += 256)
            atomicAdd(&lcnt[entries[i] & mask], 1);
        __syncthreads();
        int a0 = lcnt[2 * tid], a1 = lcnt[2 * tid + 1];
        int pr = a0 + a1;
        ps[tid] = pr;
        __syncthreads();
#pragma unroll
        for (int off = 1; off < 256; off <<= 1) {
            int x = (tid >= off) ? ps[tid - off] : 0;
            __syncthreads();
            ps[tid] += x;
            __syncthreads();
        }
        int excl = ps[tid] - pr;
        lrp[2 * tid] = excl;
        lrp[2 * tid + 1] = excl + a0;
        __syncthreads();
        for (int i = tid; i < nNodes; i += 256)
            rp2[g0 + i] = make_int2(s + lrp[i], s + lrp[i] + lcnt[i]);
        for (int i = s + tid; i < e; i += 256) {
            int p = entries[i];
            int dl = p & mask;
            int off = s + lrp[dl] + atomicAdd(&lcur[dl], 1);
            list[off] = p >> shift;
        }
    } else {
        // Y1 GEMM: K=64, NO=128 (W1l rows 128B, staged swizzled in 16KB)
        const int gb = b - NBUCK;
        const int lane = tid & 63;
        const int wv = tid >> 6;
        const int rbase = gb * 128 + wv * 32;
        const int lr = lane & 15;
        const int kg = lane >> 4;
#pragma unroll
        for (int i = 0; i < 4; ++i) {
            int idx = tid + i * 256;
            int row = idx >> 3, bc = (idx & 7) << 4;
            *reinterpret_cast<uint4*>(lds + wswz(row, bc, 128)) =
                *reinterpret_cast<const uint4*>((const char*)W1l + idx * 16);
        }
        short8 xb[2][2];
#pragma unroll
        for (int t = 0; t < 2; ++t) {
            int row = min(rbase + t * 16 + lr, NM - 1);
#pragma unroll
            for (int kt = 0; kt < 2; ++kt)
                xb[t][kt] = *reinterpret_cast<const short8*>(
                    mxb + (size_t)row * FEAT + kt * 32 + kg * 8);
        }
        __syncthreads();
        f32x4 acc[2][8];
#pragma unroll
        for (int t = 0; t < 2; ++t)
#pragma unroll
            for (int c = 0; c < 8; ++c) acc[t][c] = (f32x4){0.f, 0.f, 0.f, 0.f};
#pragma unroll
        for (int cg = 0; cg < 8; ++cg) {
            short8 wf[2];
#pragma unroll
            for (int kt = 0; kt < 2; ++kt)
                wf[kt] = *reinterpret_cast<const short8*>(
                    lds + wswz(cg * 16 + lr, kt * 64 + kg * 16, 128));
#pragma unroll
            for (int kt = 0; kt < 2; ++kt)
#pragma unroll
                for (int t = 0; t < 2; ++t)
                    acc[t][cg] = __builtin_amdgcn_mfma_f32_16x16x32_bf16(
                        wf[kt], xb[t][kt], acc[t][cg], 0, 0, 0);
        }
#pragma unroll
        for (int t = 0; t < 2; ++t) {
            const int u = rbase + t * 16 + lr;
            if (u >= NM) continue;
#pragma unroll
            for (int cg = 0; cg < 8; ++cg) {
                const int h0 = cg * 16 + kg * 4;
                uint2 o = make_uint2(pk2(acc[t][cg][0], acc[t][cg][1]),
                                     pk2(acc[t][cg][2], acc[t][cg][3]));
                *reinterpret_cast<uint2*>(Y1 + (size_t)u * HID + h0) = o;
            }
        }
    }
}

// ---------------- gather + mean + c1 + relu epilogue (conv1) ----------------
__global__ __launch_bounds__(256) void k_gather_relu(const unsigned short* __restrict__ Y1,
                                                     const int2* __restrict__ rp2,
                                                     const int* __restrict__ list,
                                                     const float* __restrict__ c1,
                                                     unsigned short* __restrict__ user_x,
                                                     int n) {
    const int node = blockIdx.x * 16 + threadIdx.x / 16;
    if (node >= n) return;
    const int c8 = (threadIdx.x % 16) * 8;
    const int2 se = rp2[node];
    const int s = se.x, e = se.y;

    float a[8];
#pragma unroll
    for (int j = 0; j < 8; ++j) a[j] = 0.f;
    int i = s;
    for (; i + 3 < e; i += 4) {
        int r0 = list[i], r1 = list[i + 1], r2 = list[i + 2], r3 = list[i + 3];
        short8 v0 = *reinterpret_cast<const short8*>(Y1 + (size_t)r0 * HID + c8);
        short8 v1 = *reinterpret_cast<const short8*>(Y1 + (size_t)r1 * HID + c8);
        short8 v2 = *reinterpret_cast<const short8*>(Y1 + (size_t)r2 * HID + c8);
        short8 v3 = *reinterpret_cast<const short8*>(Y1 + (size_t)r3 * HID + c8);
#pragma unroll
        for (int j = 0; j < 8; ++j)
            a[j] += (b2f((unsigned short)v0[j]) + b2f((unsigned short)v1[j]))
                  + (b2f((unsigned short)v2[j]) + b2f((unsigned short)v3[j]));
    }
    for (; i < e; ++i) {
        int r0 = list[i];
        short8 v0 = *reinterpret_cast<const short8*>(Y1 + (size_t)r0 * HID + c8);
#pragma unroll
        for (int j = 0; j < 8; ++j) a[j] += b2f((unsigned short)v0[j]);
    }
    const float sc = 1.0f / (float)max(e - s, 1);
    float4 cv0 = *reinterpret_cast<const float4*>(c1 + c8);
    float4 cv1 = *reinterpret_cast<const float4*>(c1 + c8 + 4);
    float r[8];
    r[0] = fmaxf(a[0] * sc + cv0.x, 0.f); r[1] = fmaxf(a[1] * sc + cv0.y, 0.f);
    r[2] = fmaxf(a[2] * sc + cv0.z, 0.f); r[3] = fmaxf(a[3] * sc + cv0.w, 0.f);
    r[4] = fmaxf(a[4] * sc + cv1.x, 0.f); r[5] = fmaxf(a[5] * sc + cv1.y, 0.f);
    r[6] = fmaxf(a[6] * sc + cv1.z, 0.f); r[7] = fmaxf(a[7] * sc + cv1.w, 0.f);
    uint4 o;
    o.x = pk2(r[0], r[1]); o.y = pk2(r[2], r[3]);
    o.z = pk2(r[4], r[5]); o.w = pk2(r[6], r[7]);
    *reinterpret_cast<uint4*>(user_x + (size_t)node * HID + c8) = o;
}

// ---------------- bf16 gather segment mean, 8-edge unrolled (mean2: movie deg ~30) ----------------
__global__ __launch_bounds__(256) void k_gather8(const unsigned short* __restrict__ src,
                                                 const int2* __restrict__ rp2,
                                                 const int* __restrict__ list,
                                                 unsigned short* __restrict__ dst,
                                                 int base, int n) {
    const int node = blockIdx.x * 16 + threadIdx.x / 16;
    if (node >= n) return;
    const int c8 = (threadIdx.x % 16) * 8;
    const int2 se = rp2[base + node];
    const int s = se.x, e = se.y;

    float a[8];
#pragma unroll
    for (int j = 0; j < 8; ++j) a[j] = 0.f;
    int i = s;
    for (; i + 7 < e; i += 8) {
        short8 v[8];
#pragma unroll
        for (int q = 0; q < 8; ++q)
            v[q] = *reinterpret_cast<const short8*>(src + (size_t)list[i + q] * HID + c8);
#pragma unroll
        for (int q = 0; q < 8; ++q)
#pragma unroll
            for (int j = 0; j < 8; ++j)
                a[j] += b2f((unsigned short)v[q][j]);
    }
    for (; i + 3 < e; i += 4) {
        short8 v[4];
#pragma unroll
        for (int q = 0; q < 4; ++q)
            v[q] = *reinterpret_cast<const short8*>(src + (size_t)list[i + q] * HID + c8);
#pragma unroll
        for (int q = 0; q < 4; ++q)
#pragma unroll
            for (int j = 0; j < 8; ++j)
                a[j] += b2f((unsigned short)v[q][j]);
    }
    for (; i < e; ++i) {
        short8 v0 = *reinterpret_cast<const short8*>(src + (size_t)list[i] * HID + c8);
#pragma unroll
        for (int j = 0; j < 8; ++j) a[j] += b2f((unsigned short)v0[j]);
    }
    const float sc = 1.0f / (float)max(e - s, 1);
    short8 o;
#pragma unroll
    for (int j = 0; j < 8; ++j) o[j] = (short)f2b(a[j] * sc);
    *reinterpret_cast<short8*>(dst + (size_t)node * HID + c8) = o;
}

// ---------------- gather Y3 -> Z = relu(mean + T3) (conv3 node update inline) ----------------
__global__ __launch_bounds__(256) void k_gather_z(const unsigned short* __restrict__ Y3,
                                                  const int2* __restrict__ rp2,
                                                  const int* __restrict__ list,
                                                  const unsigned short* __restrict__ T3,
                                                  unsigned short* __restrict__ Z, int n) {
    const int node = blockIdx.x * 16 + threadIdx.x / 16;
    if (node >= n) return;
    const int c8 = (threadIdx.x % 16) * 8;
    const int2 se = rp2[node];
    const int s = se.x, e = se.y;

    float a[8];
#pragma unroll
    for (int j = 0; j < 8; ++j) a[j] = 0.f;
    int i = s;
    for (; i + 3 < e; i += 4) {
        int r0 = list[i], r1 = list[i + 1], r2 = list[i + 2], r3 = list[i + 3];
        short8 v0 = *reinterpret_cast<const short8*>(Y3 + (size_t)r0 * HID + c8);
        short8 v1 = *reinterpret_cast<const short8*>(Y3 + (size_t)r1 * HID + c8);
        short8 v2 = *reinterpret_cast<const short8*>(Y3 + (size_t)r2 * HID + c8);
        short8 v3 = *reinterpret_cast<const short8*>(Y3 + (size_t)r3 * HID + c8);
#pragma unroll
        for (int j = 0; j < 8; ++j)
            a[j] += (b2f((unsigned short)v0[j]) + b2f((unsigned short)v1[j]))
                  + (b2f((unsigned short)v2[j]) + b2f((unsigned short)v3[j]));
    }
    for (; i < e; ++i) {
        int r0 = list[i];
        short8 v0 = *reinterpret_cast<const short8*>(Y3 + (size_t)r0 * HID + c8);
#pragma unroll
        for (int j = 0; j < 8; ++j) a[j] += b2f((unsigned short)v0[j]);
    }
    const float sc = 1.0f / (float)max(e - s, 1);
    short8 t3 = *reinterpret_cast<const short8*>(T3 + (size_t)node * HID + c8);
    short8 o;
#pragma unroll
    for (int j = 0; j < 8; ++j)
        o[j] = (short)f2b(fmaxf(a[j] * sc + b2f((unsigned short)t3[j]), 0.f));
    *reinterpret_cast<short8*>(Z + (size_t)node * HID + c8) = o;
}

// ================= swapped-operand MFMA GEMM, W staged in LDS =================
template<int K, int NO, bool AVEC, bool RELU, bool F32OUT>
__global__ __launch_bounds__(256) void k_mf2(const unsigned short* __restrict__ X,
                                             const unsigned short* __restrict__ W,
                                             const float* __restrict__ vec,
                                             void* __restrict__ Yv, int M) {
    constexpr int KT = K / 32;
    constexpr int CG = NO / 16;
    constexpr int WB = NO * K * 2;
    constexpr int RB = K * 2;
    __shared__ __align__(16) char lds[WB];
    const int tid = threadIdx.x;
    const int lane = tid & 63;
    const int wv = tid >> 6;
    const int rbase = blockIdx.x * 128 + wv * 32;
    const int lr = lane & 15;
    const int kg = lane >> 4;

#pragma unroll
    for (int i = 0; i < WB / 16 / 256; ++i) {
        int idx = tid + i * 256;
        int row = idx / (RB / 16);
        int bc = (idx % (RB / 16)) * 16;
        *reinterpret_cast<uint4*>(lds + wswz(row, bc, RB)) =
            *reinterpret_cast<const uint4*>((const char*)W + idx * 16);
    }

    short8 xb[2][KT];
#pragma unroll
    for (int t = 0; t < 2; ++t) {
        int row = min(rbase + t * 16 + lr, M - 1);
#pragma unroll
        for (int kt = 0; kt < KT; ++kt)
            xb[t][kt] = *reinterpret_cast<const short8*>(
                X + (size_t)row * K + kt * 32 + kg * 8);
    }
    __syncthreads();

    f32x4 acc[2][CG];
#pragma unroll
    for (int t = 0; t < 2; ++t)
#pragma unroll
        for (int c = 0; c < CG; ++c) acc[t][c] = (f32x4){0.f, 0.f, 0.f, 0.f};

#pragma unroll
    for (int cg = 0; cg < CG; ++cg) {
        short8 wf[KT];
#pragma unroll
        for (int kt = 0; kt < KT; ++kt)
            wf[kt] = *reinterpret_cast<const short8*>(
                lds + wswz(cg * 16 + lr, kt * 64 + kg * 16, RB));
#pragma unroll
        for (int kt = 0; kt < KT; ++kt)
#pragma unroll
            for (int t = 0; t < 2; ++t)
                acc[t][cg] = __builtin_amdgcn_mfma_f32_16x16x32_bf16(
                    wf[kt], xb[t][kt], acc[t][cg], 0, 0, 0);
    }

#pragma unroll
    for (int t = 0; t < 2; ++t) {
        const int u = rbase + t * 16 + lr;
        if (u >= M) continue;
#pragma unroll
        for (int cg = 0; cg < CG; ++cg) {
            const int h0 = cg * 16 + kg * 4;
            float v[4];
#pragma unroll
            for (int r = 0; r < 4; ++r) v[r] = acc[t][cg][r];
            if (AVEC) {
                float4 vv = *reinterpret_cast<const float4*>(vec + h0);
                v[0] += vv.x; v[1] += vv.y; v[2] += vv.z; v[3] += vv.w;
            }
            if (RELU)
#pragma unroll
                for (int r = 0; r < 4; ++r) v[r] = fmaxf(v[r], 0.f);
            if (F32OUT) {
                float4 o = make_float4(v[0], v[1], v[2], v[3]);
                *reinterpret_cast<float4*>((float*)Yv + (size_t)u * NO + h0) = o;
            } else {
                uint2 o = make_uint2(pk2(v[0], v[1]), pk2(v[2], v[3]));
                *reinterpret_cast<uint2*>((unsigned short*)Yv + (size_t)u * NO + h0) = o;
            }
        }
    }
}

// ================= fused movie chain + Y3 projection || T3 GEMM (matching LDS profiles) =================
// blocks [0, FM_BLKS): Z = relu(mean2@W2l^T + mxb@W2r^T + b2); movie_z; out; Y3 = Z@W3l^T
// blocks [FM_BLKS, FM_BLKS+T3_BLKS): T3 = user_x @ W3r^T + b3
__global__ __launch_bounds__(256) void k_fm_t3(
        const unsigned short* __restrict__ mean2, const unsigned short* __restrict__ mxb,
        const unsigned short* __restrict__ W2l, const unsigned short* __restrict__ W2r,
        const float* __restrict__ b2, unsigned short* __restrict__ movie_z,
        const unsigned short* __restrict__ Wl2, const float* __restrict__ bl2,
        const unsigned short* __restrict__ W3l, unsigned short* __restrict__ Y3,
        float* __restrict__ out, int M,
        const unsigned short* __restrict__ user_x, const unsigned short* __restrict__ W3r,
        const float* __restrict__ b3, unsigned short* __restrict__ T3) {
    __shared__ __align__(16) char lds[65536];
    const int tid = threadIdx.x;
    const int lane = tid & 63;
    const int wv = tid >> 6;
    const int lr = lane & 15;
    const int kg = lane >> 4;

    if (blockIdx.x >= FM_BLKS) {
        // ---------- T3 = user_x @ W3r^T + b3 (W3r staged in 32KB) ----------
        const int gb = blockIdx.x - FM_BLKS;
        const int rbase = gb * 128 + wv * 32;
#pragma unroll
        for (int i = 0; i < 8; ++i) {
            int idx = tid + i * 256;
            int row = idx >> 4, bc = (idx & 15) << 4;
            *reinterpret_cast<uint4*>(lds + wswz(row, bc, 256)) =
                *reinterpret_cast<const uint4*>((const char*)W3r + idx * 16);
        }
        short8 xb[2][4];
#pragma unroll
        for (int t = 0; t < 2; ++t) {
            int row = min(rbase + t * 16 + lr, NU - 1);
#pragma unroll
            for (int kt = 0; kt < 4; ++kt)
                xb[t][kt] = *reinterpret_cast<const short8*>(
                    user_x + (size_t)row * HID + kt * 32 + kg * 8);
        }
        __syncthreads();
        f32x4 acc[2][8];
#pragma unroll
        for (int t = 0; t < 2; ++t)
#pragma unroll
            for (int c = 0; c < 8; ++c) acc[t][c] = (f32x4){0.f, 0.f, 0.f, 0.f};
#pragma unroll
        for (int cg = 0; cg < 8; ++cg) {
            short8 wf[4];
#pragma unroll
            for (int kt = 0; kt < 4; ++kt)
                wf[kt] = *reinterpret_cast<const short8*>(
                    lds + wswz(cg * 16 + lr, kt * 64 + kg * 16, 256));
#pragma unroll
            for (int kt = 0; kt < 4; ++kt)
#pragma unroll
                for (int t = 0; t < 2; ++t)
                    acc[t][cg] = __builtin_amdgcn_mfma_f32_16x16x32_bf16(
                        wf[kt], xb[t][kt], acc[t][cg], 0, 0, 0);
        }
#pragma unroll
        for (int t = 0; t < 2; ++t) {
            const int u = rbase + t * 16 + lr;
            if (u >= NU) continue;
#pragma unroll
            for (int cg = 0; cg < 8; ++cg) {
                const int h0 = cg * 16 + kg * 4;
                float4 vv = *reinterpret_cast<const float4*>(b3 + h0);
                uint2 o = make_uint2(pk2(acc[t][cg][0] + vv.x, acc[t][cg][1] + vv.y),
                                     pk2(acc[t][cg][2] + vv.z, acc[t][cg][3] + vv.w));
                *reinterpret_cast<uint2*>(T3 + (size_t)u * HID + h0) = o;
            }
        }
        return;
    }

    // ---------- fused movie chain ----------
    const int rbase = blockIdx.x * 128 + wv * 32;
    // stage W2l (32KB, 256B rows), W2r (16KB, 128B rows), Wl2 (16KB, 256B rows)
#pragma unroll
    for (int i = 0; i < 8; ++i) {
        int idx = tid + i * 256;
        int row = idx >> 4, bc = (idx & 15) << 4;
        *reinterpret_cast<uint4*>(lds + wswz(row, bc, 256)) =
            *reinterpret_cast<const uint4*>((const char*)W2l + idx * 16);
    }
#pragma unroll
    for (int i = 0; i < 4; ++i) {
        int idx = tid + i * 256;
        int row = idx >> 3, bc = (idx & 7) << 4;
        *reinterpret_cast<uint4*>(lds + 32768 + wswz(row, bc, 128)) =
            *reinterpret_cast<const uint4*>((const char*)W2r + idx * 16);
        int row2 = idx >> 4, bc2 = (idx & 15) << 4;
        *reinterpret_cast<uint4*>(lds + 49152 + wswz(row2, bc2, 256)) =
            *reinterpret_cast<const uint4*>((const char*)Wl2 + idx * 16);
    }

    short8 xa[2][4], xc[2][2];
#pragma unroll
    for (int t = 0; t < 2; ++t) {
        int row = min(rbase + t * 16 + lr, M - 1);
#pragma unroll
        for (int kt = 0; kt < 4; ++kt)
            xa[t][kt] = *reinterpret_cast<const short8*>(
                mean2 + (size_t)row * HID + kt * 32 + kg * 8);
#pragma unroll
        for (int kt = 0; kt < 2; ++kt)
            xc[t][kt] = *reinterpret_cast<const short8*>(
                mxb + (size_t)row * FEAT + kt * 32 + kg * 8);
    }
    __syncthreads();

    f32x4 acc[2][8];
#pragma unroll
    for (int t = 0; t < 2; ++t)
#pragma unroll
        for (int c = 0; c < 8; ++c) acc[t][c] = (f32x4){0.f, 0.f, 0.f, 0.f};

#pragma unroll
    for (int cg = 0; cg < 8; ++cg) {
        short8 wl[4], wr[2];
#pragma unroll
        for (int kt = 0; kt < 4; ++kt)
            wl[kt] = *reinterpret_cast<const short8*>(
                lds + wswz(cg * 16 + lr, kt * 64 + kg * 16, 256));
#pragma unroll
        for (int kt = 0; kt < 2; ++kt)
            wr[kt] = *reinterpret_cast<const short8*>(
                lds + 32768 + wswz(cg * 16 + lr, kt * 64 + kg * 16, 128));
#pragma unroll
        for (int kt = 0; kt < 4; ++kt)
#pragma unroll
            for (int t = 0; t < 2; ++t)
                acc[t][cg] = __builtin_amdgcn_mfma_f32_16x16x32_bf16(
                    wl[kt], xa[t][kt], acc[t][cg], 0, 0, 0);
#pragma unroll
        for (int kt = 0; kt < 2; ++kt)
#pragma unroll
            for (int t = 0; t < 2; ++t)
                acc[t][cg] = __builtin_amdgcn_mfma_f32_16x16x32_bf16(
                    wr[kt], xc[t][kt], acc[t][cg], 0, 0, 0);
    }
    __syncthreads();   // W2l reads done -> Z may overwrite [0,32K)

    // epilogue 1: relu(acc + b2) -> Z (LDS) + global movie_z
#pragma unroll
    for (int t = 0; t < 2; ++t) {
        const int ul = wv * 32 + t * 16 + lr;
        const int u = rbase + t * 16 + lr;
#pragma unroll
        for (int cg = 0; cg < 8; ++cg) {
            const int h0 = cg * 16 + kg * 4;
            float4 vv = *reinterpret_cast<const float4*>(b2 + h0);
            float v0 = fmaxf(acc[t][cg][0] + vv.x, 0.f);
            float v1 = fmaxf(acc[t][cg][1] + vv.y, 0.f);
            float v2 = fmaxf(acc[t][cg][2] + vv.z, 0.f);
            float v3 = fmaxf(acc[t][cg][3] + vv.w, 0.f);
            uint2 pk = make_uint2(pk2(v0, v1), pk2(v2, v3));
            *reinterpret_cast<uint2*>(lds + wswz(ul, h0 * 2, 256)) = pk;
            if (u < M)
                *reinterpret_cast<uint2*>(movie_z + (size_t)u * HID + h0) = pk;
        }
    }
    __syncthreads();

    // GEMM2: out = Z @ Wlin2^T + blin2
    short8 zb[2][4];
#pragma unroll
    for (int t = 0; t < 2; ++t) {
        const int ul = wv * 32 + t * 16 + lr;
#pragma unroll
        for (int kt = 0; kt < 4; ++kt)
            zb[t][kt] = *reinterpret_cast<const short8*>(
                lds + wswz(ul, kt * 64 + kg * 16, 256));
    }
    f32x4 a2[2][4];
#pragma unroll
    for (int t = 0; t < 2; ++t)
#pragma unroll
        for (int c = 0; c < 4; ++c) a2[t][c] = (f32x4){0.f, 0.f, 0.f, 0.f};
#pragma unroll
    for (int cg = 0; cg < 4; ++cg) {
        short8 wf[4];
#pragma unroll
        for (int kt = 0; kt < 4; ++kt)
            wf[kt] = *reinterpret_cast<const short8*>(
                lds + 49152 + wswz(cg * 16 + lr, kt * 64 + kg * 16, 256));
#pragma unroll
        for (int kt = 0; kt < 4; ++kt)
#pragma unroll
            for (int t = 0; t < 2; ++t)
                a2[t][cg] = __builtin_amdgcn_mfma_f32_16x16x32_bf16(
                    wf[kt], zb[t][kt], a2[t][cg], 0, 0, 0);
    }
#pragma unroll
    for (int t = 0; t < 2; ++t) {
        const int u = rbase + t * 16 + lr;
        if (u >= M) continue;
#pragma unroll
        for (int cg = 0; cg < 4; ++cg) {
            const int o0 = cg * 16 + kg * 4;
            float4 bb = *reinterpret_cast<const float4*>(bl2 + o0);
            float4 o = make_float4(a2[t][cg][0] + bb.x, a2[t][cg][1] + bb.y,
                                   a2[t][cg][2] + bb.z, a2[t][cg][3] + bb.w);
            *reinterpret_cast<float4*>(out + (size_t)u * OUTD + o0) = o;
        }
    }
    __syncthreads();   // Wl2 + W2r reads done -> W3l may overwrite [32K,64K)

    // stage W3l (32KB, 256B rows) at [32K,64K)
#pragma unroll
    for (int i = 0; i < 8; ++i) {
        int idx = tid + i * 256;
        int row = idx >> 4, bc = (idx & 15) << 4;
        *reinterpret_cast<uint4*>(lds + 32768 + wswz(row, bc, 256)) =
            *reinterpret_cast<const uint4*>((const char*)W3l + idx * 16);
    }
    __syncthreads();

    // GEMM3: Y3 = Z @ W3l^T
    f32x4 a3[2][8];
#pragma unroll
    for (int t = 0; t < 2; ++t)
#pragma unroll
        for (int c = 0; c < 8; ++c) a3[t][c] = (f32x4){0.f, 0.f, 0.f, 0.f};
#pragma unroll
    for (int cg = 0; cg < 8; ++cg) {
        short8 wf[4];
#pragma unroll
        for (int kt = 0; kt < 4; ++kt)
            wf[kt] = *reinterpret_cast<const short8*>(
                lds + 32768 + wswz(cg * 16 + lr, kt * 64 + kg * 16, 256));
#pragma unroll
        for (int kt = 0; kt < 4; ++kt)
#pragma unroll
            for (int t = 0; t < 2; ++t)
                a3[t][cg] = __builtin_amdgcn_mfma_f32_16x16x32_bf16(
                    wf[kt], zb[t][kt], a3[t][cg], 0, 0, 0);
    }
#pragma unroll
    for (int t = 0; t < 2; ++t) {
        const int u = rbase + t * 16 + lr;
        if (u >= M) continue;
#pragma unroll
        for (int cg = 0; cg < 8; ++cg) {
            const int h0 = cg * 16 + kg * 4;
            uint2 pk = make_uint2(pk2(a3[t][cg][0], a3[t][cg][1]),
                                  pk2(a3[t][cg][2], a3[t][cg][3]));
            *reinterpret_cast<uint2*>(Y3 + (size_t)u * HID + h0) = pk;
        }
    }
}

extern "C" void kernel_launch(void* const* d_in, const int* in_sizes, int n_in,
                              void* d_out, int out_size, void* d_ws, size_t ws_size,
                              hipStream_t stream) {
    const float* movie_x  = (const float*)d_in[0];
    const int*   user_idx = (const int*)d_in[1];
    const int*   movie_idx= (const int*)d_in[2];
    const int*   tuples   = (const int*)d_in[3];
    const float* user_emb = (const float*)d_in[4];
    const float* W1l = (const float*)d_in[5];
    const float* b1  = (const float*)d_in[6];
    const float* W1r = (const float*)d_in[7];
    const float* W2l = (const float*)d_in[8];
    const float* b2  = (const float*)d_in[9];
    const float* W2r = (const float*)d_in[10];
    const float* W3l = (const float*)d_in[11];
    const float* b3  = (const float*)d_in[12];
    const float* W3r = (const float*)d_in[13];
    const float* Wlin1 = (const float*)d_in[14];
    const float* blin1 = (const float*)d_in[15];
    const float* Wlin2 = (const float*)d_in[16];
    const float* blin2 = (const float*)d_in[17];

    float* out = (float*)d_out;

    // ---- workspace layout ----
    char* p = (char*)d_ws;
    int* gcur = (int*)p;  p += 360 * 4;
    int* entries = (int*)p; p += (size_t)NBUCK * CAP * 4;
    int2* rp2  = (int2*)p; p += (size_t)NTOT * 8;
    int* list  = (int*)p;  p += (size_t)NBUCK * CAP * 4;
    float* c1  = (float*)p; p += 128 * 4;
    unsigned short* wb = (unsigned short*)p; p += (size_t)CVT_TOT * 2;
    unsigned short* W1l_b  = wb;
    unsigned short* W2l_b  = wb + 8192;
    unsigned short* W2r_b  = wb + 24576;
    unsigned short* W3l_b  = wb + 32768;
    unsigned short* W3r_b  = wb + 49152;
    unsigned short* Wlin1_b= wb + 65536;
    unsigned short* Wlin2_b= wb + 73728;
    unsigned short* mxb    = wb + 81920;                              // [NM][64]
    unsigned short* Y1     = (unsigned short*)p; p += (size_t)NM * HID * 2;
    unsigned short* user_x = (unsigned short*)p; p += (size_t)NU * HID * 2;
    unsigned short* mean2  = (unsigned short*)p; p += (size_t)NM * HID * 2;
    unsigned short* movie_z= (unsigned short*)p; p += (size_t)NM * HID * 2;
    unsigned short* Y3     = (unsigned short*)p; p += (size_t)NM * HID * 2;
    unsigned short* T3     = (unsigned short*)p; p += (size_t)NU * HID * 2;
    unsigned short* Z      = (unsigned short*)p; p += (size_t)NU * HID * 2;

    // ---- pass 1: partition (fixed-cap buckets) + cvt + idx + c1 ----
    hipMemsetAsync(gcur, 0, NBUCK * sizeof(int), stream);
    k_part_misc<<<NPBLK + CVT_BLKS + IDX_BLKS + 1, 256, 0, stream>>>(
        user_idx, movie_idx, gcur, entries,
        W1l, W2l, W2r, W3l, W3r, Wlin1, Wlin2, movie_x, wb,
        tuples, out + (size_t)(NU + NM) * OUTD, user_emb, W1r, b1, c1);

    // ---- pass 2: per-bucket CSR || Y1 = movie_x @ W1l^T ----
    k_csr_y1<<<NBUCK + Y1_BLKS, 256, 0, stream>>>(gcur, entries, rp2, list,
                                                  mxb, W1l_b, Y1);

    // ---- conv1: gather(Y1) + c1 + relu -> user_x ----
    k_gather_relu<<<(NU + 15) / 16, 256, 0, stream>>>(Y1, rp2, list, c1, user_x, NU);

    // ---- mean2 gather (standalone, zero-LDS, 8-deep unroll) ----
    k_gather8<<<(NM + 15) / 16, 256, 0, stream>>>(user_x, rp2, list, mean2, NU, NM);

    // ---- fused movie chain || T3 GEMM (matching LDS-GEMM profiles) ----
    k_fm_t3<<<FM_BLKS + T3_BLKS, 256, 0, stream>>>(
        mean2, mxb, W2l_b, W2r_b, b2, movie_z, Wlin2_b, blin2, W3l_b, Y3,
        out + (size_t)NU * OUTD, NM, user_x, W3r_b, b3, T3);

    // ---- conv3: gather(Y3) + T3 + relu -> Z ----
    k_gather_z<<<(NU + 15) / 16, 256, 0, stream>>>(Y3, rp2, list, T3, Z, NU);

    // ---- lin1: out = Z @ Wlin1^T + blin1 ----
    k_mf2<HID, OUTD, true, false, true><<<(NU + 127) / 128, 256, 0, stream>>>(
        Z, Wlin1_b, blin1, out, NU);
}

// Round 15
// 153.213 us; speedup vs baseline: 1.0829x; 1.0526x over previous
//
#include <hip/hip_runtime.h>

typedef __attribute__((ext_vector_type(8))) short short8;   // 8 bf16 (4 VGPR)
typedef __attribute__((ext_vector_type(4))) float f32x4;    // MFMA acc

static const int NU = 100000;
static const int NM = 20000;
static const int NE = 600000;
static const int FEAT = 64;
static const int HID = 128;
static const int OUTD = 64;
static const int NTOT = NU + NM;
static const int CVT_TOT = 81920 + NM * FEAT;   // weights + movie_x
static const int CVT_BLKS = (CVT_TOT + 255) / 256;
static const int IDX_BLKS = (100000 + 255) / 256;

// bucket geometry: users 512 nodes/bucket, movies 128 nodes/bucket
static const int UB_SHIFT = 9;
static const int MB_SHIFT = 7;
static const int NBU = (NU + 511) >> 9;           // 196
static const int NBM = (NM + 127) >> 7;           // 157
static const int NBUCK = NBU + NBM;               // 353
static const int EPB = 4096;
static const int NPBLK = (NE + EPB - 1) / EPB;    // 147
static const int CAP = 8192;                      // fixed bucket capacity (2x headroom)
static const int Y1_BLKS = (NM + 127) / 128;      // 157
static const int FM_BLKS = (NM + 127) / 128;      // 157 (fused movie chain)
static const int T3_BLKS = (NU + 127) / 128;      // 782

__device__ inline float b2f(unsigned short h) {
    unsigned int u = ((unsigned int)h) << 16;
    float f; __builtin_memcpy(&f, &u, 4); return f;
}
__device__ inline unsigned short f2b(float f) {
    unsigned int u; __builtin_memcpy(&u, &f, 4);
    u += 0x7FFFu + ((u >> 16) & 1u);            // RNE
    return (unsigned short)(u >> 16);
}
__device__ inline unsigned int pk2(float a, float b) {
    return (unsigned int)f2b(a) | ((unsigned int)f2b(b) << 16);
}
// XOR swizzle within a row: spreads 16B frag slots across banks (G4)
__device__ inline int wswz(int row, int bc, int rowbytes) {
    return row * rowbytes + (bc ^ ((row & 7) << 4));
}

// ---------------- pass 1 merged: edge partition (fixed-cap buckets) + cvt + idx + c1 ----------------
__global__ __launch_bounds__(256) void k_part_misc(
        const int* __restrict__ ui, const int* __restrict__ mi,
        int* __restrict__ gcur, int* __restrict__ entries,
        const float* __restrict__ w1l, const float* __restrict__ w2l,
        const float* __restrict__ w2r, const float* __restrict__ w3l,
        const float* __restrict__ w3r, const float* __restrict__ wl1,
        const float* __restrict__ wl2, const float* __restrict__ mx,
        unsigned short* __restrict__ dst,
        const int* __restrict__ tpl, float* __restrict__ oidx,
        const float* __restrict__ ue, const float* __restrict__ w1r,
        const float* __restrict__ b1, float* __restrict__ c1) {
    __shared__ int h[NBUCK], base[NBUCK], cur[NBUCK];
    const int b = blockIdx.x;
    const int tid = threadIdx.x;
    if (b < NPBLK) {
        for (int i = tid; i < NBUCK; i += 256) h[i] = 0;
        __syncthreads();
        int eu[EPB / 256], em[EPB / 256];
#pragma unroll
        for (int it = 0; it < EPB / 256; ++it) {
            int e = b * EPB + it * 256 + tid;
            if (e < NE) {
                eu[it] = ui[e]; em[it] = mi[e];
                atomicAdd(&h[eu[it] >> UB_SHIFT], 1);
                atomicAdd(&h[NBU + (em[it] >> MB_SHIFT)], 1);
            } else eu[it] = -1;
        }
        __syncthreads();
        for (int i = tid; i < NBUCK; i += 256) {
            int c = h[i];
            base[i] = c ? (i * CAP + atomicAdd(&gcur[i], c)) : 0;
            cur[i] = 0;
        }
        __syncthreads();
#pragma unroll
        for (int it = 0; it < EPB / 256; ++it) {
            if (eu[it] < 0) continue;
            int u = eu[it], m = em[it];
            int bu = u >> UB_SHIFT;
            int o1 = base[bu] + atomicAdd(&cur[bu], 1);
            entries[o1] = (m << UB_SHIFT) | (u & 511);
            int bm = NBU + (m >> MB_SHIFT);
            int o2 = base[bm] + atomicAdd(&cur[bm], 1);
            entries[o2] = (u << MB_SHIFT) | (m & 127);
        }
    } else if (b < NPBLK + CVT_BLKS) {
        int g = (b - NPBLK) * 256 + tid;
        if (g >= CVT_TOT) return;
        const float* s; int o;
        if      (g < 8192)   { s = w1l; o = g; }
        else if (g < 24576)  { s = w2l; o = g - 8192; }
        else if (g < 32768)  { s = w2r; o = g - 24576; }
        else if (g < 49152)  { s = w3l; o = g - 32768; }
        else if (g < 65536)  { s = w3r; o = g - 49152; }
        else if (g < 73728)  { s = wl1; o = g - 65536; }
        else if (g < 81920)  { s = wl2; o = g - 73728; }
        else                 { s = mx;  o = g - 81920; }
        dst[g] = f2b(s[o]);
    } else if (b < NPBLK + CVT_BLKS + IDX_BLKS) {
        int i = (b - NPBLK - CVT_BLKS) * 256 + tid;
        if (i < 100000) {
            oidx[i] = (float)tpl[i];
            oidx[100000 + i] = (float)(tpl[100000 + i] + NU);
        }
    } else {
        int hh = tid;
        if (hh < HID) {
            float a = 0.f;
#pragma unroll 16
            for (int k = 0; k < HID; ++k) a += ue[k] * w1r[hh * HID + k];
            c1[hh] = a + b1[hh];
        }
    }
}

// ---------------- pass 2 merged: per-bucket CSR build || Y1 = mxb @ W1l^T ----------------
__global__ __launch_bounds__(256) void k_csr_y1(
        const int* __restrict__ gcur, const int* __restrict__ entries,
        int2* __restrict__ rp2, int* __restrict__ list,
        const unsigned short* __restrict__ mxb, const unsigned short* __restrict__ W1l,
        unsigned short* __restrict__ Y1) {
    __shared__ __align__(16) char lds[16384];
    const int b = blockIdx.x;
    const int tid = threadIdx.x;
    if (b < NBUCK) {
        int* lcnt = (int*)lds;          // 512
        int* lrp  = lcnt + 512;         // 512
        int* lcur = lrp + 512;          // 512
        int* ps   = lcur + 512;         // 256
        const int s = b * CAP;
        const int e = s + gcur[b];
        const bool isU = b < NBU;
        const int shift = isU ? UB_SHIFT : MB_SHIFT;
        const int mask = isU ? 511 : 127;
        const int n0 = isU ? (b << UB_SHIFT) : ((b - NBU) << MB_SHIFT);
        const int nNodes = isU ? min(512, NU - n0) : min(128, NM - n0);
        const int g0 = isU ? n0 : NU + n0;

        for (int i = tid; i < 512; i += 256) { lcnt[i] = 0; lcur[i] = 0; }
        __syncthreads();
        for (int i = s + tid; i < e; i += 256)
            atomicAdd(&lcnt[entries[i] & mask], 1);
        __syncthreads();
        int a0 = lcnt[2 * tid], a1 = lcnt[2 * tid + 1];
        int pr = a0 + a1;
        ps[tid] = pr;
        __syncthreads();
#pragma unroll
        for (int off = 1; off < 256; off <<= 1) {
            int x = (tid >= off) ? ps[tid - off] : 0;
            __syncthreads();
            ps[tid] += x;
            __syncthreads();
        }
        int excl = ps[tid] - pr;
        lrp[2 * tid] = excl;
        lrp[2 * tid + 1] = excl + a0;
        __syncthreads();
        for (int i = tid; i < nNodes; i += 256)
            rp2[g0 + i] = make_int2(s + lrp[i], s + lrp[i] + lcnt[i]);
        for (int i = s + tid; i < e; i += 256) {
            int p = entries[i];
            int dl = p & mask;
            int off = s + lrp[dl] + atomicAdd(&lcur[dl], 1);
            list[off] = p >> shift;
        }
    } else {
        // Y1 GEMM: K=64, NO=128 (W1l rows 128B, staged swizzled in 16KB)
        const int gb = b - NBUCK;
        const int lane = tid & 63;
        const int wv = tid >> 6;
        const int rbase = gb * 128 + wv * 32;
        const int lr = lane & 15;
        const int kg = lane >> 4;
#pragma unroll
        for (int i = 0; i < 4; ++i) {
            int idx = tid + i * 256;
            int row = idx >> 3, bc = (idx & 7) << 4;
            *reinterpret_cast<uint4*>(lds + wswz(row, bc, 128)) =
                *reinterpret_cast<const uint4*>((const char*)W1l + idx * 16);
        }
        short8 xb[2][2];
#pragma unroll
        for (int t = 0; t < 2; ++t) {
            int row = min(rbase + t * 16 + lr, NM - 1);
#pragma unroll
            for (int kt = 0; kt < 2; ++kt)
                xb[t][kt] = *reinterpret_cast<const short8*>(
                    mxb + (size_t)row * FEAT + kt * 32 + kg * 8);
        }
        __syncthreads();
        f32x4 acc[2][8];
#pragma unroll
        for (int t = 0; t < 2; ++t)
#pragma unroll
            for (int c = 0; c < 8; ++c) acc[t][c] = (f32x4){0.f, 0.f, 0.f, 0.f};
#pragma unroll
        for (int cg = 0; cg < 8; ++cg) {
            short8 wf[2];
#pragma unroll
            for (int kt = 0; kt < 2; ++kt)
                wf[kt] = *reinterpret_cast<const short8*>(
                    lds + wswz(cg * 16 + lr, kt * 64 + kg * 16, 128));
#pragma unroll
            for (int kt = 0; kt < 2; ++kt)
#pragma unroll
                for (int t = 0; t < 2; ++t)
                    acc[t][cg] = __builtin_amdgcn_mfma_f32_16x16x32_bf16(
                        wf[kt], xb[t][kt], acc[t][cg], 0, 0, 0);
        }
#pragma unroll
        for (int t = 0; t < 2; ++t) {
            const int u = rbase + t * 16 + lr;
            if (u >= NM) continue;
#pragma unroll
            for (int cg = 0; cg < 8; ++cg) {
                const int h0 = cg * 16 + kg * 4;
                uint2 o = make_uint2(pk2(acc[t][cg][0], acc[t][cg][1]),
                                     pk2(acc[t][cg][2], acc[t][cg][3]));
                *reinterpret_cast<uint2*>(Y1 + (size_t)u * HID + h0) = o;
            }
        }
    }
}

// ---------------- gather + mean + c1 + relu epilogue (conv1) ----------------
__global__ __launch_bounds__(256) void k_gather_relu(const unsigned short* __restrict__ Y1,
                                                     const int2* __restrict__ rp2,
                                                     const int* __restrict__ list,
                                                     const float* __restrict__ c1,
                                                     unsigned short* __restrict__ user_x,
                                                     int n) {
    const int node = blockIdx.x * 16 + threadIdx.x / 16;
    if (node >= n) return;
    const int c8 = (threadIdx.x % 16) * 8;
    const int2 se = rp2[node];
    const int s = se.x, e = se.y;

    float a[8];
#pragma unroll
    for (int j = 0; j < 8; ++j) a[j] = 0.f;
    int i = s;
    for (; i + 3 < e; i += 4) {
        int r0 = list[i], r1 = list[i + 1], r2 = list[i + 2], r3 = list[i + 3];
        short8 v0 = *reinterpret_cast<const short8*>(Y1 + (size_t)r0 * HID + c8);
        short8 v1 = *reinterpret_cast<const short8*>(Y1 + (size_t)r1 * HID + c8);
        short8 v2 = *reinterpret_cast<const short8*>(Y1 + (size_t)r2 * HID + c8);
        short8 v3 = *reinterpret_cast<const short8*>(Y1 + (size_t)r3 * HID + c8);
#pragma unroll
        for (int j = 0; j < 8; ++j)
            a[j] += (b2f((unsigned short)v0[j]) + b2f((unsigned short)v1[j]))
                  + (b2f((unsigned short)v2[j]) + b2f((unsigned short)v3[j]));
    }
    for (; i < e; ++i) {
        int r0 = list[i];
        short8 v0 = *reinterpret_cast<const short8*>(Y1 + (size_t)r0 * HID + c8);
#pragma unroll
        for (int j = 0; j < 8; ++j) a[j] += b2f((unsigned short)v0[j]);
    }
    const float sc = 1.0f / (float)max(e - s, 1);
    float4 cv0 = *reinterpret_cast<const float4*>(c1 + c8);
    float4 cv1 = *reinterpret_cast<const float4*>(c1 + c8 + 4);
    float r[8];
    r[0] = fmaxf(a[0] * sc + cv0.x, 0.f); r[1] = fmaxf(a[1] * sc + cv0.y, 0.f);
    r[2] = fmaxf(a[2] * sc + cv0.z, 0.f); r[3] = fmaxf(a[3] * sc + cv0.w, 0.f);
    r[4] = fmaxf(a[4] * sc + cv1.x, 0.f); r[5] = fmaxf(a[5] * sc + cv1.y, 0.f);
    r[6] = fmaxf(a[6] * sc + cv1.z, 0.f); r[7] = fmaxf(a[7] * sc + cv1.w, 0.f);
    uint4 o;
    o.x = pk2(r[0], r[1]); o.y = pk2(r[2], r[3]);
    o.z = pk2(r[4], r[5]); o.w = pk2(r[6], r[7]);
    *reinterpret_cast<uint4*>(user_x + (size_t)node * HID + c8) = o;
}

// ---------------- bf16 gather segment mean, 8-edge unrolled (mean2: movie deg ~30) ----------------
__global__ __launch_bounds__(256) void k_gather8(const unsigned short* __restrict__ src,
                                                 const int2* __restrict__ rp2,
                                                 const int* __restrict__ list,
                                                 unsigned short* __restrict__ dst,
                                                 int base, int n) {
    const int node = blockIdx.x * 16 + threadIdx.x / 16;
    if (node >= n) return;
    const int c8 = (threadIdx.x % 16) * 8;
    const int2 se = rp2[base + node];
    const int s = se.x, e = se.y;

    float a[8];
#pragma unroll
    for (int j = 0; j < 8; ++j) a[j] = 0.f;
    int i = s;
    for (; i + 7 < e; i += 8) {
        short8 v[8];
#pragma unroll
        for (int q = 0; q < 8; ++q)
            v[q] = *reinterpret_cast<const short8*>(src + (size_t)list[i + q] * HID + c8);
#pragma unroll
        for (int q = 0; q < 8; ++q)
#pragma unroll
            for (int j = 0; j < 8; ++j)
                a[j] += b2f((unsigned short)v[q][j]);
    }
    for (; i + 3 < e; i += 4) {
        short8 v[4];
#pragma unroll
        for (int q = 0; q < 4; ++q)
            v[q] = *reinterpret_cast<const short8*>(src + (size_t)list[i + q] * HID + c8);
#pragma unroll
        for (int q = 0; q < 4; ++q)
#pragma unroll
            for (int j = 0; j < 8; ++j)
                a[j] += b2f((unsigned short)v[q][j]);
    }
    for (; i < e; ++i) {
        short8 v0 = *reinterpret_cast<const short8*>(src + (size_t)list[i] * HID + c8);
#pragma unroll
        for (int j = 0; j < 8; ++j) a[j] += b2f((unsigned short)v0[j]);
    }
    const float sc = 1.0f / (float)max(e - s, 1);
    short8 o;
#pragma unroll
    for (int j = 0; j < 8; ++j) o[j] = (short)f2b(a[j] * sc);
    *reinterpret_cast<short8*>(dst + (size_t)node * HID + c8) = o;
}

// ---------------- conv3 + lin1 fused: gather(Y3)+T3+relu -> Z tile (LDS) -> out = Z@Wlin1^T ----------------
// Block = 16 nodes (NU = 6250*16, no tail). LDS = 4KB Z tile + 16KB Wlin1 = 20KB
// -> occupancy stays wave-limited (8 blocks/CU x 4 waves = 32 waves), no TLP loss for the gather.
__global__ __launch_bounds__(256) void k_gz_lin1(const unsigned short* __restrict__ Y3,
                                                 const int2* __restrict__ rp2,
                                                 const int* __restrict__ list,
                                                 const unsigned short* __restrict__ T3,
                                                 const unsigned short* __restrict__ Wl1,
                                                 const float* __restrict__ bl1,
                                                 float* __restrict__ out, int n) {
    __shared__ __align__(16) char lds[4096 + 16384];   // [0,4K) Z tile; [4K,20K) Wlin1
    const int tid = threadIdx.x;
    const int rbase = blockIdx.x * 16;
    const int node_l = tid / 16;
    const int node = rbase + node_l;
    const int c8 = (tid % 16) * 8;

    // stage Wlin1 [64][128] bf16 (256B rows, swizzled)
#pragma unroll
    for (int i = 0; i < 4; ++i) {
        int idx = tid + i * 256;
        int row = idx >> 4, bc = (idx & 15) << 4;
        *reinterpret_cast<uint4*>(lds + 4096 + wswz(row, bc, 256)) =
            *reinterpret_cast<const uint4*>((const char*)Wl1 + idx * 16);
    }

    // gather phase: Z[node_l][c8..c8+7] = relu(mean(Y3[nbrs]) + T3)
    {
        const int2 se = rp2[node];
        const int s = se.x, e = se.y;
        float a[8];
#pragma unroll
        for (int j = 0; j < 8; ++j) a[j] = 0.f;
        int i = s;
        for (; i + 3 < e; i += 4) {
            int r0 = list[i], r1 = list[i + 1], r2 = list[i + 2], r3 = list[i + 3];
            short8 v0 = *reinterpret_cast<const short8*>(Y3 + (size_t)r0 * HID + c8);
            short8 v1 = *reinterpret_cast<const short8*>(Y3 + (size_t)r1 * HID + c8);
            short8 v2 = *reinterpret_cast<const short8*>(Y3 + (size_t)r2 * HID + c8);
            short8 v3 = *reinterpret_cast<const short8*>(Y3 + (size_t)r3 * HID + c8);
#pragma unroll
            for (int j = 0; j < 8; ++j)
                a[j] += (b2f((unsigned short)v0[j]) + b2f((unsigned short)v1[j]))
                      + (b2f((unsigned short)v2[j]) + b2f((unsigned short)v3[j]));
        }
        for (; i < e; ++i) {
            int r0 = list[i];
            short8 v0 = *reinterpret_cast<const short8*>(Y3 + (size_t)r0 * HID + c8);
#pragma unroll
            for (int j = 0; j < 8; ++j) a[j] += b2f((unsigned short)v0[j]);
        }
        const float sc = 1.0f / (float)max(e - s, 1);
        short8 t3 = *reinterpret_cast<const short8*>(T3 + (size_t)node * HID + c8);
        float z[8];
#pragma unroll
        for (int j = 0; j < 8; ++j)
            z[j] = fmaxf(a[j] * sc + b2f((unsigned short)t3[j]), 0.f);
        uint4 o;
        o.x = pk2(z[0], z[1]); o.y = pk2(z[2], z[3]);
        o.z = pk2(z[4], z[5]); o.w = pk2(z[6], z[7]);
        *reinterpret_cast<uint4*>(lds + wswz(node_l, c8 * 2, 256)) = o;
    }
    __syncthreads();

    // lin1 phase: out[16][64] = Z(16x128) @ Wlin1^T; wave w handles 16 output cols
    const int lane = tid & 63;
    const int lr = lane & 15;
    const int kg = lane >> 4;
    const int cg = tid >> 6;           // 0..3 output col group
    f32x4 acc = (f32x4){0.f, 0.f, 0.f, 0.f};
#pragma unroll
    for (int kt = 0; kt < 4; ++kt) {
        short8 zf = *reinterpret_cast<const short8*>(
            lds + wswz(lr, kt * 64 + kg * 16, 256));
        short8 wf = *reinterpret_cast<const short8*>(
            lds + 4096 + wswz(cg * 16 + lr, kt * 64 + kg * 16, 256));
        acc = __builtin_amdgcn_mfma_f32_16x16x32_bf16(wf, zf, acc, 0, 0, 0);
    }
    // D: col(lane&15) = Z row (node), row = h offset -> out[rbase+lr][cg*16+kg*4+r]
    {
        const int h0 = cg * 16 + kg * 4;
        float4 bb = *reinterpret_cast<const float4*>(bl1 + h0);
        float4 o = make_float4(acc[0] + bb.x, acc[1] + bb.y,
                               acc[2] + bb.z, acc[3] + bb.w);
        *reinterpret_cast<float4*>(out + (size_t)(rbase + lr) * OUTD + h0) = o;
    }
}

// ================= fused movie chain + Y3 projection || T3 GEMM (matching LDS profiles) =================
__global__ __launch_bounds__(256) void k_fm_t3(
        const unsigned short* __restrict__ mean2, const unsigned short* __restrict__ mxb,
        const unsigned short* __restrict__ W2l, const unsigned short* __restrict__ W2r,
        const float* __restrict__ b2, unsigned short* __restrict__ movie_z,
        const unsigned short* __restrict__ Wl2, const float* __restrict__ bl2,
        const unsigned short* __restrict__ W3l, unsigned short* __restrict__ Y3,
        float* __restrict__ out, int M,
        const unsigned short* __restrict__ user_x, const unsigned short* __restrict__ W3r,
        const float* __restrict__ b3, unsigned short* __restrict__ T3) {
    __shared__ __align__(16) char lds[65536];
    const int tid = threadIdx.x;
    const int lane = tid & 63;
    const int wv = tid >> 6;
    const int lr = lane & 15;
    const int kg = lane >> 4;

    if (blockIdx.x >= FM_BLKS) {
        // ---------- T3 = user_x @ W3r^T + b3 (W3r staged in 32KB) ----------
        const int gb = blockIdx.x - FM_BLKS;
        const int rbase = gb * 128 + wv * 32;
#pragma unroll
        for (int i = 0; i < 8; ++i) {
            int idx = tid + i * 256;
            int row = idx >> 4, bc = (idx & 15) << 4;
            *reinterpret_cast<uint4*>(lds + wswz(row, bc, 256)) =
                *reinterpret_cast<const uint4*>((const char*)W3r + idx * 16);
        }
        short8 xb[2][4];
#pragma unroll
        for (int t = 0; t < 2; ++t) {
            int row = min(rbase + t * 16 + lr, NU - 1);
#pragma unroll
            for (int kt = 0; kt < 4; ++kt)
                xb[t][kt] = *reinterpret_cast<const short8*>(
                    user_x + (size_t)row * HID + kt * 32 + kg * 8);
        }
        __syncthreads();
        f32x4 acc[2][8];
#pragma unroll
        for (int t = 0; t < 2; ++t)
#pragma unroll
            for (int c = 0; c < 8; ++c) acc[t][c] = (f32x4){0.f, 0.f, 0.f, 0.f};
#pragma unroll
        for (int cg = 0; cg < 8; ++cg) {
            short8 wf[4];
#pragma unroll
            for (int kt = 0; kt < 4; ++kt)
                wf[kt] = *reinterpret_cast<const short8*>(
                    lds + wswz(cg * 16 + lr, kt * 64 + kg * 16, 256));
#pragma unroll
            for (int kt = 0; kt < 4; ++kt)
#pragma unroll
                for (int t = 0; t < 2; ++t)
                    acc[t][cg] = __builtin_amdgcn_mfma_f32_16x16x32_bf16(
                        wf[kt], xb[t][kt], acc[t][cg], 0, 0, 0);
        }
#pragma unroll
        for (int t = 0; t < 2; ++t) {
            const int u = rbase + t * 16 + lr;
            if (u >= NU) continue;
#pragma unroll
            for (int cg = 0; cg < 8; ++cg) {
                const int h0 = cg * 16 + kg * 4;
                float4 vv = *reinterpret_cast<const float4*>(b3 + h0);
                uint2 o = make_uint2(pk2(acc[t][cg][0] + vv.x, acc[t][cg][1] + vv.y),
                                     pk2(acc[t][cg][2] + vv.z, acc[t][cg][3] + vv.w));
                *reinterpret_cast<uint2*>(T3 + (size_t)u * HID + h0) = o;
            }
        }
        return;
    }

    // ---------- fused movie chain ----------
    const int rbase = blockIdx.x * 128 + wv * 32;
#pragma unroll
    for (int i = 0; i < 8; ++i) {
        int idx = tid + i * 256;
        int row = idx >> 4, bc = (idx & 15) << 4;
        *reinterpret_cast<uint4*>(lds + wswz(row, bc, 256)) =
            *reinterpret_cast<const uint4*>((const char*)W2l + idx * 16);
    }
#pragma unroll
    for (int i = 0; i < 4; ++i) {
        int idx = tid + i * 256;
        int row = idx >> 3, bc = (idx & 7) << 4;
        *reinterpret_cast<uint4*>(lds + 32768 + wswz(row, bc, 128)) =
            *reinterpret_cast<const uint4*>((const char*)W2r + idx * 16);
        int row2 = idx >> 4, bc2 = (idx & 15) << 4;
        *reinterpret_cast<uint4*>(lds + 49152 + wswz(row2, bc2, 256)) =
            *reinterpret_cast<const uint4*>((const char*)Wl2 + idx * 16);
    }

    short8 xa[2][4], xc[2][2];
#pragma unroll
    for (int t = 0; t < 2; ++t) {
        int row = min(rbase + t * 16 + lr, M - 1);
#pragma unroll
        for (int kt = 0; kt < 4; ++kt)
            xa[t][kt] = *reinterpret_cast<const short8*>(
                mean2 + (size_t)row * HID + kt * 32 + kg * 8);
#pragma unroll
        for (int kt = 0; kt < 2; ++kt)
            xc[t][kt] = *reinterpret_cast<const short8*>(
                mxb + (size_t)row * FEAT + kt * 32 + kg * 8);
    }
    __syncthreads();

    f32x4 acc[2][8];
#pragma unroll
    for (int t = 0; t < 2; ++t)
#pragma unroll
        for (int c = 0; c < 8; ++c) acc[t][c] = (f32x4){0.f, 0.f, 0.f, 0.f};

#pragma unroll
    for (int cg = 0; cg < 8; ++cg) {
        short8 wl[4], wr[2];
#pragma unroll
        for (int kt = 0; kt < 4; ++kt)
            wl[kt] = *reinterpret_cast<const short8*>(
                lds + wswz(cg * 16 + lr, kt * 64 + kg * 16, 256));
#pragma unroll
        for (int kt = 0; kt < 2; ++kt)
            wr[kt] = *reinterpret_cast<const short8*>(
                lds + 32768 + wswz(cg * 16 + lr, kt * 64 + kg * 16, 128));
#pragma unroll
        for (int kt = 0; kt < 4; ++kt)
#pragma unroll
            for (int t = 0; t < 2; ++t)
                acc[t][cg] = __builtin_amdgcn_mfma_f32_16x16x32_bf16(
                    wl[kt], xa[t][kt], acc[t][cg], 0, 0, 0);
#pragma unroll
        for (int kt = 0; kt < 2; ++kt)
#pragma unroll
            for (int t = 0; t < 2; ++t)
                acc[t][cg] = __builtin_amdgcn_mfma_f32_16x16x32_bf16(
                    wr[kt], xc[t][kt], acc[t][cg], 0, 0, 0);
    }
    __syncthreads();   // W2l reads done -> Z may overwrite [0,32K)

#pragma unroll
    for (int t = 0; t < 2; ++t) {
        const int ul = wv * 32 + t * 16 + lr;
        const int u = rbase + t * 16 + lr;
#pragma unroll
        for (int cg = 0; cg < 8; ++cg) {
            const int h0 = cg * 16 + kg * 4;
            float4 vv = *reinterpret_cast<const float4*>(b2 + h0);
            float v0 = fmaxf(acc[t][cg][0] + vv.x, 0.f);
            float v1 = fmaxf(acc[t][cg][1] + vv.y, 0.f);
            float v2 = fmaxf(acc[t][cg][2] + vv.z, 0.f);
            float v3 = fmaxf(acc[t][cg][3] + vv.w, 0.f);
            uint2 pk = make_uint2(pk2(v0, v1), pk2(v2, v3));
            *reinterpret_cast<uint2*>(lds + wswz(ul, h0 * 2, 256)) = pk;
            if (u < M)
                *reinterpret_cast<uint2*>(movie_z + (size_t)u * HID + h0) = pk;
        }
    }
    __syncthreads();

    short8 zb[2][4];
#pragma unroll
    for (int t = 0; t < 2; ++t) {
        const int ul = wv * 32 + t * 16 + lr;
#pragma unroll
        for (int kt = 0; kt < 4; ++kt)
            zb[t][kt] = *reinterpret_cast<const short8*>(
                lds + wswz(ul, kt * 64 + kg * 16, 256));
    }
    f32x4 a2[2][4];
#pragma unroll
    for (int t = 0; t < 2; ++t)
#pragma unroll
        for (int c = 0; c < 4; ++c) a2[t][c] = (f32x4){0.f, 0.f, 0.f, 0.f};
#pragma unroll
    for (int cg = 0; cg < 4; ++cg) {
        short8 wf[4];
#pragma unroll
        for (int kt = 0; kt < 4; ++kt)
            wf[kt] = *reinterpret_cast<const short8*>(
                lds + 49152 + wswz(cg * 16 + lr, kt * 64 + kg * 16, 256));
#pragma unroll
        for (int kt = 0; kt < 4; ++kt)
#pragma unroll
            for (int t = 0; t < 2; ++t)
                a2[t][cg] = __builtin_amdgcn_mfma_f32_16x16x32_bf16(
                    wf[kt], zb[t][kt], a2[t][cg], 0, 0, 0);
    }
#pragma unroll
    for (int t = 0; t < 2; ++t) {
        const int u = rbase + t * 16 + lr;
        if (u >= M) continue;
#pragma unroll
        for (int cg = 0; cg < 4; ++cg) {
            const int o0 = cg * 16 + kg * 4;
            float4 bb = *reinterpret_cast<const float4*>(bl2 + o0);
            float4 o = make_float4(a2[t][cg][0] + bb.x, a2[t][cg][1] + bb.y,
                                   a2[t][cg][2] + bb.z, a2[t][cg][3] + bb.w);
            *reinterpret_cast<float4*>(out + (size_t)u * OUTD + o0) = o;
        }
    }
    __syncthreads();   // Wl2 + W2r reads done -> W3l may overwrite [32K,64K)

#pragma unroll
    for (int i = 0; i < 8; ++i) {
        int idx = tid + i * 256;
        int row = idx >> 4, bc = (idx & 15) << 4;
        *reinterpret_cast<uint4*>(lds + 32768 + wswz(row, bc, 256)) =
            *reinterpret_cast<const uint4*>((const char*)W3l + idx * 16);
    }
    __syncthreads();

    f32x4 a3[2][8];
#pragma unroll
    for (int t = 0; t < 2; ++t)
#pragma unroll
        for (int c = 0; c < 8; ++c) a3[t][c] = (f32x4){0.f, 0.f, 0.f, 0.f};
#pragma unroll
    for (int cg = 0; cg < 8; ++cg) {
        short8 wf[4];
#pragma unroll
        for (int kt = 0; kt < 4; ++kt)
            wf[kt] = *reinterpret_cast<const short8*>(
                lds + 32768 + wswz(cg * 16 + lr, kt * 64 + kg * 16, 256));
#pragma unroll
        for (int kt = 0; kt < 4; ++kt)
#pragma unroll
            for (int t = 0; t < 2; ++t)
                a3[t][cg] = __builtin_amdgcn_mfma_f32_16x16x32_bf16(
                    wf[kt], zb[t][kt], a3[t][cg], 0, 0, 0);
    }
#pragma unroll
    for (int t = 0; t < 2; ++t) {
        const int u = rbase + t * 16 + lr;
        if (u >= M) continue;
#pragma unroll
        for (int cg = 0; cg < 8; ++cg) {
            const int h0 = cg * 16 + kg * 4;
            uint2 pk = make_uint2(pk2(a3[t][cg][0], a3[t][cg][1]),
                                  pk2(a3[t][cg][2], a3[t][cg][3]));
            *reinterpret_cast<uint2*>(Y3 + (size_t)u * HID + h0) = pk;
        }
    }
}

extern "C" void kernel_launch(void* const* d_in, const int* in_sizes, int n_in,
                              void* d_out, int out_size, void* d_ws, size_t ws_size,
                              hipStream_t stream) {
    const float* movie_x  = (const float*)d_in[0];
    const int*   user_idx = (const int*)d_in[1];
    const int*   movie_idx= (const int*)d_in[2];
    const int*   tuples   = (const int*)d_in[3];
    const float* user_emb = (const float*)d_in[4];
    const float* W1l = (const float*)d_in[5];
    const float* b1  = (const float*)d_in[6];
    const float* W1r = (const float*)d_in[7];
    const float* W2l = (const float*)d_in[8];
    const float* b2  = (const float*)d_in[9];
    const float* W2r = (const float*)d_in[10];
    const float* W3l = (const float*)d_in[11];
    const float* b3  = (const float*)d_in[12];
    const float* W3r = (const float*)d_in[13];
    const float* Wlin1 = (const float*)d_in[14];
    const float* blin1 = (const float*)d_in[15];
    const float* Wlin2 = (const float*)d_in[16];
    const float* blin2 = (const float*)d_in[17];

    float* out = (float*)d_out;

    // ---- workspace layout ----
    char* p = (char*)d_ws;
    int* gcur = (int*)p;  p += 360 * 4;
    int* entries = (int*)p; p += (size_t)NBUCK * CAP * 4;
    int2* rp2  = (int2*)p; p += (size_t)NTOT * 8;
    int* list  = (int*)p;  p += (size_t)NBUCK * CAP * 4;
    float* c1  = (float*)p; p += 128 * 4;
    unsigned short* wb = (unsigned short*)p; p += (size_t)CVT_TOT * 2;
    unsigned short* W1l_b  = wb;
    unsigned short* W2l_b  = wb + 8192;
    unsigned short* W2r_b  = wb + 24576;
    unsigned short* W3l_b  = wb + 32768;
    unsigned short* W3r_b  = wb + 49152;
    unsigned short* Wlin1_b= wb + 65536;
    unsigned short* Wlin2_b= wb + 73728;
    unsigned short* mxb    = wb + 81920;                              // [NM][64]
    unsigned short* Y1     = (unsigned short*)p; p += (size_t)NM * HID * 2;
    unsigned short* user_x = (unsigned short*)p; p += (size_t)NU * HID * 2;
    unsigned short* mean2  = (unsigned short*)p; p += (size_t)NM * HID * 2;
    unsigned short* movie_z= (unsigned short*)p; p += (size_t)NM * HID * 2;
    unsigned short* Y3     = (unsigned short*)p; p += (size_t)NM * HID * 2;
    unsigned short* T3     = (unsigned short*)p; p += (size_t)NU * HID * 2;

    // ---- pass 1: partition (fixed-cap buckets) + cvt + idx + c1 ----
    hipMemsetAsync(gcur, 0, NBUCK * sizeof(int), stream);
    k_part_misc<<<NPBLK + CVT_BLKS + IDX_BLKS + 1, 256, 0, stream>>>(
        user_idx, movie_idx, gcur, entries,
        W1l, W2l, W2r, W3l, W3r, Wlin1, Wlin2, movie_x, wb,
        tuples, out + (size_t)(NU + NM) * OUTD, user_emb, W1r, b1, c1);

    // ---- pass 2: per-bucket CSR || Y1 = movie_x @ W1l^T ----
    k_csr_y1<<<NBUCK + Y1_BLKS, 256, 0, stream>>>(gcur, entries, rp2, list,
                                                  mxb, W1l_b, Y1);

    // ---- conv1: gather(Y1) + c1 + relu -> user_x ----
    k_gather_relu<<<(NU + 15) / 16, 256, 0, stream>>>(Y1, rp2, list, c1, user_x, NU);

    // ---- mean2 gather (standalone, zero-LDS, 8-deep unroll) ----
    k_gather8<<<(NM + 15) / 16, 256, 0, stream>>>(user_x, rp2, list, mean2, NU, NM);

    // ---- fused movie chain || T3 GEMM ----
    k_fm_t3<<<FM_BLKS + T3_BLKS, 256, 0, stream>>>(
        mean2, mxb, W2l_b, W2r_b, b2, movie_z, Wlin2_b, blin2, W3l_b, Y3,
        out + (size_t)NU * OUTD, NM, user_x, W3r_b, b3, T3);

    // ---- conv3 + lin1 fused: gather(Y3)+T3+relu -> Z tile -> out (no Z round-trip) ----
    k_gz_lin1<<<NU / 16, 256, 0, stream>>>(Y3, rp2, list, T3, Wlin1_b, blin1, out, NU);
}

// Round 16
// 147.347 us; speedup vs baseline: 1.1260x; 1.0398x over previous
//
#include <hip/hip_runtime.h>

typedef __attribute__((ext_vector_type(8))) short short8;   // 8 bf16 (4 VGPR)
typedef __attribute__((ext_vector_type(4))) float f32x4;    // MFMA acc

static const int NU = 100000;
static const int NM = 20000;
static const int NE = 600000;
static const int FEAT = 64;
static const int HID = 128;
static const int OUTD = 64;
static const int NTOT = NU + NM;
static const int CVT_TOT = 81920 + NM * FEAT;   // weights + movie_x
static const int CVT_BLKS = (CVT_TOT + 255) / 256;
static const int IDX_BLKS = (100000 + 255) / 256;

// bucket geometry: users 512 nodes/bucket, movies 128 nodes/bucket
static const int UB_SHIFT = 9;
static const int MB_SHIFT = 7;
static const int NBU = (NU + 511) >> 9;           // 196
static const int NBM = (NM + 127) >> 7;           // 157
static const int NBUCK = NBU + NBM;               // 353
static const int EPB = 4096;
static const int NPBLK = (NE + EPB - 1) / EPB;    // 147
static const int CAP = 8192;                      // fixed bucket capacity (2x headroom)
static const int FM_BLKS = (NM + 127) / 128;      // 157 (fused movie chain)
static const int T3_BLKS = (NU + 127) / 128;      // 782

__device__ inline float b2f(unsigned short h) {
    unsigned int u = ((unsigned int)h) << 16;
    float f; __builtin_memcpy(&f, &u, 4); return f;
}
__device__ inline unsigned short f2b(float f) {
    unsigned int u; __builtin_memcpy(&u, &f, 4);
    u += 0x7FFFu + ((u >> 16) & 1u);            // RNE
    return (unsigned short)(u >> 16);
}
__device__ inline unsigned int pk2(float a, float b) {
    return (unsigned int)f2b(a) | ((unsigned int)f2b(b) << 16);
}
// XOR swizzle within a row: spreads 16B frag slots across banks (G4)
__device__ inline int wswz(int row, int bc, int rowbytes) {
    return row * rowbytes + (bc ^ ((row & 7) << 4));
}

// ---------------- pass 1 merged: edge partition (fixed-cap buckets) + cvt + idx + c1 ----------------
__global__ __launch_bounds__(256) void k_part_misc(
        const int* __restrict__ ui, const int* __restrict__ mi,
        int* __restrict__ gcur, int* __restrict__ entries,
        const float* __restrict__ w1l, const float* __restrict__ w2l,
        const float* __restrict__ w2r, const float* __restrict__ w3l,
        const float* __restrict__ w3r, const float* __restrict__ wl1,
        const float* __restrict__ wl2, const float* __restrict__ mx,
        unsigned short* __restrict__ dst,
        const int* __restrict__ tpl, float* __restrict__ oidx,
        const float* __restrict__ ue, const float* __restrict__ w1r,
        const float* __restrict__ b1, float* __restrict__ c1) {
    __shared__ int h[NBUCK], base[NBUCK], cur[NBUCK];
    const int b = blockIdx.x;
    const int tid = threadIdx.x;
    if (b < NPBLK) {
        for (int i = tid; i < NBUCK; i += 256) h[i] = 0;
        __syncthreads();
        int eu[EPB / 256], em[EPB / 256];
#pragma unroll
        for (int it = 0; it < EPB / 256; ++it) {
            int e = b * EPB + it * 256 + tid;
            if (e < NE) {
                eu[it] = ui[e]; em[it] = mi[e];
                atomicAdd(&h[eu[it] >> UB_SHIFT], 1);
                atomicAdd(&h[NBU + (em[it] >> MB_SHIFT)], 1);
            } else eu[it] = -1;
        }
        __syncthreads();
        for (int i = tid; i < NBUCK; i += 256) {
            int c = h[i];
            base[i] = c ? (i * CAP + atomicAdd(&gcur[i], c)) : 0;
            cur[i] = 0;
        }
        __syncthreads();
#pragma unroll
        for (int it = 0; it < EPB / 256; ++it) {
            if (eu[it] < 0) continue;
            int u = eu[it], m = em[it];
            int bu = u >> UB_SHIFT;
            int o1 = base[bu] + atomicAdd(&cur[bu], 1);
            entries[o1] = (m << UB_SHIFT) | (u & 511);
            int bm = NBU + (m >> MB_SHIFT);
            int o2 = base[bm] + atomicAdd(&cur[bm], 1);
            entries[o2] = (u << MB_SHIFT) | (m & 127);
        }
    } else if (b < NPBLK + CVT_BLKS) {
        int g = (b - NPBLK) * 256 + tid;
        if (g >= CVT_TOT) return;
        const float* s; int o;
        if      (g < 8192)   { s = w1l; o = g; }
        else if (g < 24576)  { s = w2l; o = g - 8192; }
        else if (g < 32768)  { s = w2r; o = g - 24576; }
        else if (g < 49152)  { s = w3l; o = g - 32768; }
        else if (g < 65536)  { s = w3r; o = g - 49152; }
        else if (g < 73728)  { s = wl1; o = g - 65536; }
        else if (g < 81920)  { s = wl2; o = g - 73728; }
        else                 { s = mx;  o = g - 81920; }
        dst[g] = f2b(s[o]);
    } else if (b < NPBLK + CVT_BLKS + IDX_BLKS) {
        int i = (b - NPBLK - CVT_BLKS) * 256 + tid;
        if (i < 100000) {
            oidx[i] = (float)tpl[i];
            oidx[100000 + i] = (float)(tpl[100000 + i] + NU);
        }
    } else {
        int hh = tid;
        if (hh < HID) {
            float a = 0.f;
#pragma unroll 16
            for (int k = 0; k < HID; ++k) a += ue[k] * w1r[hh * HID + k];
            c1[hh] = a + b1[hh];
        }
    }
}

// ---------------- pass 2: per-bucket CSR build in LDS (rp2 = (start,end) per node) ----------------
__global__ __launch_bounds__(256) void k_csr(const int* __restrict__ gcur,
                                             const int* __restrict__ entries,
                                             int2* __restrict__ rp2,
                                             int* __restrict__ list) {
    __shared__ int lcnt[512], lrp[512], lcur[512], ps[256];
    const int b = blockIdx.x;
    const int tid = threadIdx.x;
    const int s = b * CAP;
    const int e = s + gcur[b];
    const bool isU = b < NBU;
    const int shift = isU ? UB_SHIFT : MB_SHIFT;
    const int mask = isU ? 511 : 127;
    const int n0 = isU ? (b << UB_SHIFT) : ((b - NBU) << MB_SHIFT);
    const int nNodes = isU ? min(512, NU - n0) : min(128, NM - n0);
    const int g0 = isU ? n0 : NU + n0;

    for (int i = tid; i < 512; i += 256) { lcnt[i] = 0; lcur[i] = 0; }
    __syncthreads();
    for (int i = s + tid; i < e; i += 256)
        atomicAdd(&lcnt[entries[i] & mask], 1);
    __syncthreads();
    int a0 = lcnt[2 * tid], a1 = lcnt[2 * tid + 1];
    int pr = a0 + a1;
    ps[tid] = pr;
    __syncthreads();
#pragma unroll
    for (int off = 1; off < 256; off <<= 1) {
        int x = (tid >= off) ? ps[tid - off] : 0;
        __syncthreads();
        ps[tid] += x;
        __syncthreads();
    }
    int excl = ps[tid] - pr;
    lrp[2 * tid] = excl;
    lrp[2 * tid + 1] = excl + a0;
    __syncthreads();
    for (int i = tid; i < nNodes; i += 256)
        rp2[g0 + i] = make_int2(s + lrp[i], s + lrp[i] + lcnt[i]);
    for (int i = s + tid; i < e; i += 256) {
        int p = entries[i];
        int dl = p & mask;
        int off = s + lrp[dl] + atomicAdd(&lcur[dl], 1);
        list[off] = p >> shift;
    }
}

// ---------------- conv1 fused: gather(movie_x, 64-wide) -> mean1 tile -> user_x = relu(mean1@W1l^T + c1) ----------------
// Block = 32 nodes (NU = 3125*32, no tail). LDS = 4KB mean1 tile + 16KB W1l = 20KB
// -> wave-limited occupancy (32 waves/CU): gather keeps full TLP, GEMM rides free.
__global__ __launch_bounds__(256) void k_g1f(const unsigned short* __restrict__ mxb,
                                             const int2* __restrict__ rp2,
                                             const int* __restrict__ list,
                                             const unsigned short* __restrict__ W1l,
                                             const float* __restrict__ c1,
                                             unsigned short* __restrict__ user_x) {
    __shared__ __align__(16) char lds[4096 + 16384];   // [0,4K) mean1 (32x64 bf16, 128B rows); [4K,20K) W1l
    const int tid = threadIdx.x;
    const int rbase = blockIdx.x * 32;

    // stage W1l [128][64] bf16 (128B rows, swizzled)
#pragma unroll
    for (int i = 0; i < 4; ++i) {
        int idx = tid + i * 256;
        int row = idx >> 3, bc = (idx & 7) << 4;
        *reinterpret_cast<uint4*>(lds + 4096 + wswz(row, bc, 128)) =
            *reinterpret_cast<const uint4*>((const char*)W1l + idx * 16);
    }

    // gather phase: 8 lanes/node, 32 nodes; movie_x rows are 64-wide (half the loads of Y1)
    {
        const int node_l = tid >> 3;
        const int node = rbase + node_l;
        const int c8 = (tid & 7) * 8;
        const int2 se = rp2[node];
        const int s = se.x, e = se.y;
        float a[8];
#pragma unroll
        for (int j = 0; j < 8; ++j) a[j] = 0.f;
        int i = s;
        for (; i + 3 < e; i += 4) {
            int r0 = list[i], r1 = list[i + 1], r2 = list[i + 2], r3 = list[i + 3];
            short8 v0 = *reinterpret_cast<const short8*>(mxb + (size_t)r0 * FEAT + c8);
            short8 v1 = *reinterpret_cast<const short8*>(mxb + (size_t)r1 * FEAT + c8);
            short8 v2 = *reinterpret_cast<const short8*>(mxb + (size_t)r2 * FEAT + c8);
            short8 v3 = *reinterpret_cast<const short8*>(mxb + (size_t)r3 * FEAT + c8);
#pragma unroll
            for (int j = 0; j < 8; ++j)
                a[j] += (b2f((unsigned short)v0[j]) + b2f((unsigned short)v1[j]))
                      + (b2f((unsigned short)v2[j]) + b2f((unsigned short)v3[j]));
        }
        for (; i < e; ++i) {
            int r0 = list[i];
            short8 v0 = *reinterpret_cast<const short8*>(mxb + (size_t)r0 * FEAT + c8);
#pragma unroll
            for (int j = 0; j < 8; ++j) a[j] += b2f((unsigned short)v0[j]);
        }
        const float sc = 1.0f / (float)max(e - s, 1);
        uint4 o;
        o.x = pk2(a[0] * sc, a[1] * sc); o.y = pk2(a[2] * sc, a[3] * sc);
        o.z = pk2(a[4] * sc, a[5] * sc); o.w = pk2(a[6] * sc, a[7] * sc);
        *reinterpret_cast<uint4*>(lds + wswz(node_l, c8 * 2, 128)) = o;
    }
    __syncthreads();

    // GEMM phase: user_x[32][128] = relu(mean1(32x64) @ W1l^T + c1)
    // wave w handles output col groups {2w, 2w+1}; D.col = node, D.row = h (contiguous 4)
    const int lane = tid & 63;
    const int lr = lane & 15;
    const int kg = lane >> 4;
    const int w = tid >> 6;
#pragma unroll
    for (int t = 0; t < 2; ++t) {
        short8 zf[2];
#pragma unroll
        for (int kt = 0; kt < 2; ++kt)
            zf[kt] = *reinterpret_cast<const short8*>(
                lds + wswz(t * 16 + lr, kt * 64 + kg * 16, 128));
#pragma unroll
        for (int cl = 0; cl < 2; ++cl) {
            const int cg = w * 2 + cl;
            f32x4 acc = (f32x4){0.f, 0.f, 0.f, 0.f};
#pragma unroll
            for (int kt = 0; kt < 2; ++kt) {
                short8 wf = *reinterpret_cast<const short8*>(
                    lds + 4096 + wswz(cg * 16 + lr, kt * 64 + kg * 16, 128));
                acc = __builtin_amdgcn_mfma_f32_16x16x32_bf16(wf, zf[kt], acc, 0, 0, 0);
            }
            const int u = rbase + t * 16 + lr;
            const int h0 = cg * 16 + kg * 4;
            float4 cv = *reinterpret_cast<const float4*>(c1 + h0);
            uint2 o = make_uint2(pk2(fmaxf(acc[0] + cv.x, 0.f), fmaxf(acc[1] + cv.y, 0.f)),
                                 pk2(fmaxf(acc[2] + cv.z, 0.f), fmaxf(acc[3] + cv.w, 0.f)));
            *reinterpret_cast<uint2*>(user_x + (size_t)u * HID + h0) = o;
        }
    }
}

// ---------------- bf16 gather segment mean, 8-edge unrolled (mean2: movie deg ~30) ----------------
__global__ __launch_bounds__(256) void k_gather8(const unsigned short* __restrict__ src,
                                                 const int2* __restrict__ rp2,
                                                 const int* __restrict__ list,
                                                 unsigned short* __restrict__ dst,
                                                 int base, int n) {
    const int node = blockIdx.x * 16 + threadIdx.x / 16;
    if (node >= n) return;
    const int c8 = (threadIdx.x % 16) * 8;
    const int2 se = rp2[base + node];
    const int s = se.x, e = se.y;

    float a[8];
#pragma unroll
    for (int j = 0; j < 8; ++j) a[j] = 0.f;
    int i = s;
    for (; i + 7 < e; i += 8) {
        short8 v[8];
#pragma unroll
        for (int q = 0; q < 8; ++q)
            v[q] = *reinterpret_cast<const short8*>(src + (size_t)list[i + q] * HID + c8);
#pragma unroll
        for (int q = 0; q < 8; ++q)
#pragma unroll
            for (int j = 0; j < 8; ++j)
                a[j] += b2f((unsigned short)v[q][j]);
    }
    for (; i + 3 < e; i += 4) {
        short8 v[4];
#pragma unroll
        for (int q = 0; q < 4; ++q)
            v[q] = *reinterpret_cast<const short8*>(src + (size_t)list[i + q] * HID + c8);
#pragma unroll
        for (int q = 0; q < 4; ++q)
#pragma unroll
            for (int j = 0; j < 8; ++j)
                a[j] += b2f((unsigned short)v[q][j]);
    }
    for (; i < e; ++i) {
        short8 v0 = *reinterpret_cast<const short8*>(src + (size_t)list[i] * HID + c8);
#pragma unroll
        for (int j = 0; j < 8; ++j) a[j] += b2f((unsigned short)v0[j]);
    }
    const float sc = 1.0f / (float)max(e - s, 1);
    short8 o;
#pragma unroll
    for (int j = 0; j < 8; ++j) o[j] = (short)f2b(a[j] * sc);
    *reinterpret_cast<short8*>(dst + (size_t)node * HID + c8) = o;
}

// ---------------- conv3 + lin1 fused: gather(Y3)+T3+relu -> Z tile (LDS) -> out = Z@Wlin1^T ----------------
__global__ __launch_bounds__(256) void k_gz_lin1(const unsigned short* __restrict__ Y3,
                                                 const int2* __restrict__ rp2,
                                                 const int* __restrict__ list,
                                                 const unsigned short* __restrict__ T3,
                                                 const unsigned short* __restrict__ Wl1,
                                                 const float* __restrict__ bl1,
                                                 float* __restrict__ out, int n) {
    __shared__ __align__(16) char lds[4096 + 16384];   // [0,4K) Z tile; [4K,20K) Wlin1
    const int tid = threadIdx.x;
    const int rbase = blockIdx.x * 16;
    const int node_l = tid / 16;
    const int node = rbase + node_l;
    const int c8 = (tid % 16) * 8;

#pragma unroll
    for (int i = 0; i < 4; ++i) {
        int idx = tid + i * 256;
        int row = idx >> 4, bc = (idx & 15) << 4;
        *reinterpret_cast<uint4*>(lds + 4096 + wswz(row, bc, 256)) =
            *reinterpret_cast<const uint4*>((const char*)Wl1 + idx * 16);
    }

    {
        const int2 se = rp2[node];
        const int s = se.x, e = se.y;
        float a[8];
#pragma unroll
        for (int j = 0; j < 8; ++j) a[j] = 0.f;
        int i = s;
        for (; i + 3 < e; i += 4) {
            int r0 = list[i], r1 = list[i + 1], r2 = list[i + 2], r3 = list[i + 3];
            short8 v0 = *reinterpret_cast<const short8*>(Y3 + (size_t)r0 * HID + c8);
            short8 v1 = *reinterpret_cast<const short8*>(Y3 + (size_t)r1 * HID + c8);
            short8 v2 = *reinterpret_cast<const short8*>(Y3 + (size_t)r2 * HID + c8);
            short8 v3 = *reinterpret_cast<const short8*>(Y3 + (size_t)r3 * HID + c8);
#pragma unroll
            for (int j = 0; j < 8; ++j)
                a[j] += (b2f((unsigned short)v0[j]) + b2f((unsigned short)v1[j]))
                      + (b2f((unsigned short)v2[j]) + b2f((unsigned short)v3[j]));
        }
        for (; i < e; ++i) {
            int r0 = list[i];
            short8 v0 = *reinterpret_cast<const short8*>(Y3 + (size_t)r0 * HID + c8);
#pragma unroll
            for (int j = 0; j < 8; ++j) a[j] += b2f((unsigned short)v0[j]);
        }
        const float sc = 1.0f / (float)max(e - s, 1);
        short8 t3 = *reinterpret_cast<const short8*>(T3 + (size_t)node * HID + c8);
        float z[8];
#pragma unroll
        for (int j = 0; j < 8; ++j)
            z[j] = fmaxf(a[j] * sc + b2f((unsigned short)t3[j]), 0.f);
        uint4 o;
        o.x = pk2(z[0], z[1]); o.y = pk2(z[2], z[3]);
        o.z = pk2(z[4], z[5]); o.w = pk2(z[6], z[7]);
        *reinterpret_cast<uint4*>(lds + wswz(node_l, c8 * 2, 256)) = o;
    }
    __syncthreads();

    const int lane = tid & 63;
    const int lr = lane & 15;
    const int kg = lane >> 4;
    const int cg = tid >> 6;
    f32x4 acc = (f32x4){0.f, 0.f, 0.f, 0.f};
#pragma unroll
    for (int kt = 0; kt < 4; ++kt) {
        short8 zf = *reinterpret_cast<const short8*>(
            lds + wswz(lr, kt * 64 + kg * 16, 256));
        short8 wf = *reinterpret_cast<const short8*>(
            lds + 4096 + wswz(cg * 16 + lr, kt * 64 + kg * 16, 256));
        acc = __builtin_amdgcn_mfma_f32_16x16x32_bf16(wf, zf, acc, 0, 0, 0);
    }
    {
        const int h0 = cg * 16 + kg * 4;
        float4 bb = *reinterpret_cast<const float4*>(bl1 + h0);
        float4 o = make_float4(acc[0] + bb.x, acc[1] + bb.y,
                               acc[2] + bb.z, acc[3] + bb.w);
        *reinterpret_cast<float4*>(out + (size_t)(rbase + lr) * OUTD + h0) = o;
    }
}

// ================= fused movie chain + Y3 projection || T3 GEMM (matching LDS profiles) =================
__global__ __launch_bounds__(256) void k_fm_t3(
        const unsigned short* __restrict__ mean2, const unsigned short* __restrict__ mxb,
        const unsigned short* __restrict__ W2l, const unsigned short* __restrict__ W2r,
        const float* __restrict__ b2, unsigned short* __restrict__ movie_z,
        const unsigned short* __restrict__ Wl2, const float* __restrict__ bl2,
        const unsigned short* __restrict__ W3l, unsigned short* __restrict__ Y3,
        float* __restrict__ out, int M,
        const unsigned short* __restrict__ user_x, const unsigned short* __restrict__ W3r,
        const float* __restrict__ b3, unsigned short* __restrict__ T3) {
    __shared__ __align__(16) char lds[65536];
    const int tid = threadIdx.x;
    const int lane = tid & 63;
    const int wv = tid >> 6;
    const int lr = lane & 15;
    const int kg = lane >> 4;

    if (blockIdx.x >= FM_BLKS) {
        // ---------- T3 = user_x @ W3r^T + b3 (W3r staged in 32KB) ----------
        const int gb = blockIdx.x - FM_BLKS;
        const int rbase = gb * 128 + wv * 32;
#pragma unroll
        for (int i = 0; i < 8; ++i) {
            int idx = tid + i * 256;
            int row = idx >> 4, bc = (idx & 15) << 4;
            *reinterpret_cast<uint4*>(lds + wswz(row, bc, 256)) =
                *reinterpret_cast<const uint4*>((const char*)W3r + idx * 16);
        }
        short8 xb[2][4];
#pragma unroll
        for (int t = 0; t < 2; ++t) {
            int row = min(rbase + t * 16 + lr, NU - 1);
#pragma unroll
            for (int kt = 0; kt < 4; ++kt)
                xb[t][kt] = *reinterpret_cast<const short8*>(
                    user_x + (size_t)row * HID + kt * 32 + kg * 8);
        }
        __syncthreads();
        f32x4 acc[2][8];
#pragma unroll
        for (int t = 0; t < 2; ++t)
#pragma unroll
            for (int c = 0; c < 8; ++c) acc[t][c] = (f32x4){0.f, 0.f, 0.f, 0.f};
#pragma unroll
        for (int cg = 0; cg < 8; ++cg) {
            short8 wf[4];
#pragma unroll
            for (int kt = 0; kt < 4; ++kt)
                wf[kt] = *reinterpret_cast<const short8*>(
                    lds + wswz(cg * 16 + lr, kt * 64 + kg * 16, 256));
#pragma unroll
            for (int kt = 0; kt < 4; ++kt)
#pragma unroll
                for (int t = 0; t < 2; ++t)
                    acc[t][cg] = __builtin_amdgcn_mfma_f32_16x16x32_bf16(
                        wf[kt], xb[t][kt], acc[t][cg], 0, 0, 0);
        }
#pragma unroll
        for (int t = 0; t < 2; ++t) {
            const int u = rbase + t * 16 + lr;
            if (u >= NU) continue;
#pragma unroll
            for (int cg = 0; cg < 8; ++cg) {
                const int h0 = cg * 16 + kg * 4;
                float4 vv = *reinterpret_cast<const float4*>(b3 + h0);
                uint2 o = make_uint2(pk2(acc[t][cg][0] + vv.x, acc[t][cg][1] + vv.y),
                                     pk2(acc[t][cg][2] + vv.z, acc[t][cg][3] + vv.w));
                *reinterpret_cast<uint2*>(T3 + (size_t)u * HID + h0) = o;
            }
        }
        return;
    }

    // ---------- fused movie chain ----------
    const int rbase = blockIdx.x * 128 + wv * 32;
#pragma unroll
    for (int i = 0; i < 8; ++i) {
        int idx = tid + i * 256;
        int row = idx >> 4, bc = (idx & 15) << 4;
        *reinterpret_cast<uint4*>(lds + wswz(row, bc, 256)) =
            *reinterpret_cast<const uint4*>((const char*)W2l + idx * 16);
    }
#pragma unroll
    for (int i = 0; i < 4; ++i) {
        int idx = tid + i * 256;
        int row = idx >> 3, bc = (idx & 7) << 4;
        *reinterpret_cast<uint4*>(lds + 32768 + wswz(row, bc, 128)) =
            *reinterpret_cast<const uint4*>((const char*)W2r + idx * 16);
        int row2 = idx >> 4, bc2 = (idx & 15) << 4;
        *reinterpret_cast<uint4*>(lds + 49152 + wswz(row2, bc2, 256)) =
            *reinterpret_cast<const uint4*>((const char*)Wl2 + idx * 16);
    }

    short8 xa[2][4], xc[2][2];
#pragma unroll
    for (int t = 0; t < 2; ++t) {
        int row = min(rbase + t * 16 + lr, M - 1);
#pragma unroll
        for (int kt = 0; kt < 4; ++kt)
            xa[t][kt] = *reinterpret_cast<const short8*>(
                mean2 + (size_t)row * HID + kt * 32 + kg * 8);
#pragma unroll
        for (int kt = 0; kt < 2; ++kt)
            xc[t][kt] = *reinterpret_cast<const short8*>(
                mxb + (size_t)row * FEAT + kt * 32 + kg * 8);
    }
    __syncthreads();

    f32x4 acc[2][8];
#pragma unroll
    for (int t = 0; t < 2; ++t)
#pragma unroll
        for (int c = 0; c < 8; ++c) acc[t][c] = (f32x4){0.f, 0.f, 0.f, 0.f};

#pragma unroll
    for (int cg = 0; cg < 8; ++cg) {
        short8 wl[4], wr[2];
#pragma unroll
        for (int kt = 0; kt < 4; ++kt)
            wl[kt] = *reinterpret_cast<const short8*>(
                lds + wswz(cg * 16 + lr, kt * 64 + kg * 16, 256));
#pragma unroll
        for (int kt = 0; kt < 2; ++kt)
            wr[kt] = *reinterpret_cast<const short8*>(
                lds + 32768 + wswz(cg * 16 + lr, kt * 64 + kg * 16, 128));
#pragma unroll
        for (int kt = 0; kt < 4; ++kt)
#pragma unroll
            for (int t = 0; t < 2; ++t)
                acc[t][cg] = __builtin_amdgcn_mfma_f32_16x16x32_bf16(
                    wl[kt], xa[t][kt], acc[t][cg], 0, 0, 0);
#pragma unroll
        for (int kt = 0; kt < 2; ++kt)
#pragma unroll
            for (int t = 0; t < 2; ++t)
                acc[t][cg] = __builtin_amdgcn_mfma_f32_16x16x32_bf16(
                    wr[kt], xc[t][kt], acc[t][cg], 0, 0, 0);
    }
    __syncthreads();   // W2l reads done -> Z may overwrite [0,32K)

#pragma unroll
    for (int t = 0; t < 2; ++t) {
        const int ul = wv * 32 + t * 16 + lr;
        const int u = rbase + t * 16 + lr;
#pragma unroll
        for (int cg = 0; cg < 8; ++cg) {
            const int h0 = cg * 16 + kg * 4;
            float4 vv = *reinterpret_cast<const float4*>(b2 + h0);
            float v0 = fmaxf(acc[t][cg][0] + vv.x, 0.f);
            float v1 = fmaxf(acc[t][cg][1] + vv.y, 0.f);
            float v2 = fmaxf(acc[t][cg][2] + vv.z, 0.f);
            float v3 = fmaxf(acc[t][cg][3] + vv.w, 0.f);
            uint2 pk = make_uint2(pk2(v0, v1), pk2(v2, v3));
            *reinterpret_cast<uint2*>(lds + wswz(ul, h0 * 2, 256)) = pk;
            if (u < M)
                *reinterpret_cast<uint2*>(movie_z + (size_t)u * HID + h0) = pk;
        }
    }
    __syncthreads();

    short8 zb[2][4];
#pragma unroll
    for (int t = 0; t < 2; ++t) {
        const int ul = wv * 32 + t * 16 + lr;
#pragma unroll
        for (int kt = 0; kt < 4; ++kt)
            zb[t][kt] = *reinterpret_cast<const short8*>(
                lds + wswz(ul, kt * 64 + kg * 16, 256));
    }
    f32x4 a2[2][4];
#pragma unroll
    for (int t = 0; t < 2; ++t)
#pragma unroll
        for (int c = 0; c < 4; ++c) a2[t][c] = (f32x4){0.f, 0.f, 0.f, 0.f};
#pragma unroll
    for (int cg = 0; cg < 4; ++cg) {
        short8 wf[4];
#pragma unroll
        for (int kt = 0; kt < 4; ++kt)
            wf[kt] = *reinterpret_cast<const short8*>(
                lds + 49152 + wswz(cg * 16 + lr, kt * 64 + kg * 16, 256));
#pragma unroll
        for (int kt = 0; kt < 4; ++kt)
#pragma unroll
            for (int t = 0; t < 2; ++t)
                a2[t][cg] = __builtin_amdgcn_mfma_f32_16x16x32_bf16(
                    wf[kt], zb[t][kt], a2[t][cg], 0, 0, 0);
    }
#pragma unroll
    for (int t = 0; t < 2; ++t) {
        const int u = rbase + t * 16 + lr;
        if (u >= M) continue;
#pragma unroll
        for (int cg = 0; cg < 4; ++cg) {
            const int o0 = cg * 16 + kg * 4;
            float4 bb = *reinterpret_cast<const float4*>(bl2 + o0);
            float4 o = make_float4(a2[t][cg][0] + bb.x, a2[t][cg][1] + bb.y,
                                   a2[t][cg][2] + bb.z, a2[t][cg][3] + bb.w);
            *reinterpret_cast<float4*>(out + (size_t)u * OUTD + o0) = o;
        }
    }
    __syncthreads();   // Wl2 + W2r reads done -> W3l may overwrite [32K,64K)

#pragma unroll
    for (int i = 0; i < 8; ++i) {
        int idx = tid + i * 256;
        int row = idx >> 4, bc = (idx & 15) << 4;
        *reinterpret_cast<uint4*>(lds + 32768 + wswz(row, bc, 256)) =
            *reinterpret_cast<const uint4*>((const char*)W3l + idx * 16);
    }
    __syncthreads();

    f32x4 a3[2][8];
#pragma unroll
    for (int t = 0; t < 2; ++t)
#pragma unroll
        for (int c = 0; c < 8; ++c) a3[t][c] = (f32x4){0.f, 0.f, 0.f, 0.f};
#pragma unroll
    for (int cg = 0; cg < 8; ++cg) {
        short8 wf[4];
#pragma unroll
        for (int kt = 0; kt < 4; ++kt)
            wf[kt] = *reinterpret_cast<const short8*>(
                lds + 32768 + wswz(cg * 16 + lr, kt * 64 + kg * 16, 256));
#pragma unroll
        for (int kt = 0; kt < 4; ++kt)
#pragma unroll
            for (int t = 0; t < 2; ++t)
                a3[t][cg] = __builtin_amdgcn_mfma_f32_16x16x32_bf16(
                    wf[kt], zb[t][kt], a3[t][cg], 0, 0, 0);
    }
#pragma unroll
    for (int t = 0; t < 2; ++t) {
        const int u = rbase + t * 16 + lr;
        if (u >= M) continue;
#pragma unroll
        for (int cg = 0; cg < 8; ++cg) {
            const int h0 = cg * 16 + kg * 4;
            uint2 pk = make_uint2(pk2(a3[t][cg][0], a3[t][cg][1]),
                                  pk2(a3[t][cg][2], a3[t][cg][3]));
            *reinterpret_cast<uint2*>(Y3 + (size_t)u * HID + h0) = pk;
        }
    }
}

extern "C" void kernel_launch(void* const* d_in, const int* in_sizes, int n_in,
                              void* d_out, int out_size, void* d_ws, size_t ws_size,
                              hipStream_t stream) {
    const float* movie_x  = (const float*)d_in[0];
    const int*   user_idx = (const int*)d_in[1];
    const int*   movie_idx= (const int*)d_in[2];
    const int*   tuples   = (const int*)d_in[3];
    const float* user_emb = (const float*)d_in[4];
    const float* W1l = (const float*)d_in[5];
    const float* b1  = (const float*)d_in[6];
    const float* W1r = (const float*)d_in[7];
    const float* W2l = (const float*)d_in[8];
    const float* b2  = (const float*)d_in[9];
    const float* W2r = (const float*)d_in[10];
    const float* W3l = (const float*)d_in[11];
    const float* b3  = (const float*)d_in[12];
    const float* W3r = (const float*)d_in[13];
    const float* Wlin1 = (const float*)d_in[14];
    const float* blin1 = (const float*)d_in[15];
    const float* Wlin2 = (const float*)d_in[16];
    const float* blin2 = (const float*)d_in[17];

    float* out = (float*)d_out;

    // ---- workspace layout ----
    char* p = (char*)d_ws;
    int* gcur = (int*)p;  p += 360 * 4;
    int* entries = (int*)p; p += (size_t)NBUCK * CAP * 4;
    int2* rp2  = (int2*)p; p += (size_t)NTOT * 8;
    int* list  = (int*)p;  p += (size_t)NBUCK * CAP * 4;
    float* c1  = (float*)p; p += 128 * 4;
    unsigned short* wb = (unsigned short*)p; p += (size_t)CVT_TOT * 2;
    unsigned short* W1l_b  = wb;
    unsigned short* W2l_b  = wb + 8192;
    unsigned short* W2r_b  = wb + 24576;
    unsigned short* W3l_b  = wb + 32768;
    unsigned short* W3r_b  = wb + 49152;
    unsigned short* Wlin1_b= wb + 65536;
    unsigned short* Wlin2_b= wb + 73728;
    unsigned short* mxb    = wb + 81920;                              // [NM][64]
    unsigned short* user_x = (unsigned short*)p; p += (size_t)NU * HID * 2;
    unsigned short* mean2  = (unsigned short*)p; p += (size_t)NM * HID * 2;
    unsigned short* movie_z= (unsigned short*)p; p += (size_t)NM * HID * 2;
    unsigned short* Y3     = (unsigned short*)p; p += (size_t)NM * HID * 2;
    unsigned short* T3     = (unsigned short*)p; p += (size_t)NU * HID * 2;

    // ---- pass 1: partition (fixed-cap buckets) + cvt + idx + c1 ----
    hipMemsetAsync(gcur, 0, NBUCK * sizeof(int), stream);
    k_part_misc<<<NPBLK + CVT_BLKS + IDX_BLKS + 1, 256, 0, stream>>>(
        user_idx, movie_idx, gcur, entries,
        W1l, W2l, W2r, W3l, W3r, Wlin1, Wlin2, movie_x, wb,
        tuples, out + (size_t)(NU + NM) * OUTD, user_emb, W1r, b1, c1);

    // ---- pass 2: per-bucket CSR ----
    k_csr<<<NBUCK, 256, 0, stream>>>(gcur, entries, rp2, list);

    // ---- conv1 fused: gather(movie_x, 64-wide) + GEMM(W1l) + c1 + relu -> user_x ----
    k_g1f<<<NU / 32, 256, 0, stream>>>(mxb, rp2, list, W1l_b, c1, user_x);

    // ---- mean2 gather (standalone, zero-LDS, 8-deep unroll) ----
    k_gather8<<<(NM + 15) / 16, 256, 0, stream>>>(user_x, rp2, list, mean2, NU, NM);

    // ---- fused movie chain || T3 GEMM ----
    k_fm_t3<<<FM_BLKS + T3_BLKS, 256, 0, stream>>>(
        mean2, mxb, W2l_b, W2r_b, b2, movie_z, Wlin2_b, blin2, W3l_b, Y3,
        out + (size_t)NU * OUTD, NM, user_x, W3r_b, b3, T3);

    // ---- conv3 + lin1 fused: gather(Y3)+T3+relu -> Z tile -> out ----
    k_gz_lin1<<<NU / 16, 256, 0, stream>>>(Y3, rp2, list, T3, Wlin1_b, blin1, out, NU);
}